// Round 3
// baseline (9037.292 us; speedup 1.0000x reference)
//
#include <hip/hip_runtime.h>
#include <hip/hip_bf16.h>

#define BB 64
#define CIN 256
#define CC 576
#define NGR 9
#define SPC 64
#define HW7 49
#define HW14 196
#define HW28 784

__device__ __constant__ int EDGE_SRC_C[24] = {1,3, 0,2,4, 1,5, 0,4,6, 1,3,5,7, 2,4,8, 3,7, 4,6,8, 5,7};
__device__ __constant__ int EDGE_OFF_C[9]  = {0,2,5,7,10,14,17,19,22};
__device__ __constant__ int EDGE_CNT_C[9]  = {2,3,2,3,4,3,2,3,2};

static __device__ __forceinline__ float bf2f(__hip_bfloat16 v){ return __bfloat162float(v); }
static __device__ __forceinline__ __hip_bfloat16 f2bf(float v){ return __float2bfloat16(v); }
// polymorphic external-input load: isbf==1 -> bf16, else fp32
static __device__ __forceinline__ float ldin(const void* p, size_t i, int isbf){
  return isbf ? bf2f(((const __hip_bfloat16*)p)[i]) : ((const float*)p)[i];
}

// ---- dtype detector: classify x as bf16(1) or fp32(0) --------------------
__global__ void detect_kernel(const unsigned short* xs, int* flag) {
  if (threadIdx.x==0 && blockIdx.x==0) {
    int plaus = 0;
    for (int i=0;i<64;i++){
      unsigned short u = xs[2*i];       // even 16-bit words
      int e = (u>>7)&0xFF;              // bf16 exponent field
      if (e>=100 && e<=140) plaus++;    // plausible for N(0,1)-ish data
    }
    *flag = (plaus >= 40) ? 1 : 0;
  }
}

// ---- conv0 + GN(36) + ReLU: [B,256,14,14] -> [B,576,7,7] bf16, 3x3 s2 p1
__global__ __launch_bounds__(448) void conv0_gn_kernel(
    const void* __restrict__ x,
    const void* __restrict__ w,      // [576,256,9]
    const void* __restrict__ bias,   // [576]
    const void* __restrict__ gamma,  // [576]
    const void* __restrict__ beta,
    const int* __restrict__ flagp,
    __hip_bfloat16* __restrict__ out) {
  const int isbf = *flagp;
  const int b = blockIdx.x, ocb = blockIdx.y, t = threadIdx.x;
  const int oc_l = t / 7, row = t % 7;
  const int oc = ocb*64 + oc_l;

  __shared__ float s_in[16][15][16];
  __shared__ float s_w[64*145];
  __shared__ float s_red[448], s_red2[448];
  __shared__ float s_stats[4][2];

  float acc[7] = {0,0,0,0,0,0,0};
  for (int icc=0; icc<CIN; icc+=16) {
    __syncthreads();
    for (int idx=t; idx<16*240; idx+=448) {
      int c = idx/240, rem = idx%240, r = rem>>4, col = rem&15;
      int iy=r-1, ix=col-1;
      float v = 0.f;
      if (iy>=0 && iy<14 && ix>=0 && ix<14)
        v = ldin(x, ((size_t)(b*CIN + icc + c))*HW14 + iy*14 + ix, isbf);
      s_in[c][r][col] = v;
    }
    for (int idx=t; idx<64*144; idx+=448) {
      int o = idx/144, rem = idx%144;
      s_w[o*145+rem] = ldin(w, ((size_t)(ocb*64+o)*CIN + icc + rem/9)*9 + rem%9, isbf);
    }
    __syncthreads();
    for (int c=0;c<16;c++){
      float wr[9];
      #pragma unroll
      for (int k=0;k<9;k++) wr[k] = s_w[oc_l*145 + c*9 + k];
      float R0[15],R1[15],R2[15];
      #pragma unroll
      for (int j=0;j<15;j++){ R0[j]=s_in[c][2*row][j]; R1[j]=s_in[c][2*row+1][j]; R2[j]=s_in[c][2*row+2][j]; }
      #pragma unroll
      for (int ox=0;ox<7;ox++){
        acc[ox] += R0[2*ox]*wr[0]+R0[2*ox+1]*wr[1]+R0[2*ox+2]*wr[2]
                 + R1[2*ox]*wr[3]+R1[2*ox+1]*wr[4]+R1[2*ox+2]*wr[5]
                 + R2[2*ox]*wr[6]+R2[2*ox+1]*wr[7]+R2[2*ox+2]*wr[8];
      }
    }
  }
  float bv = ldin(bias, oc, isbf);
  float v[7], s=0.f, ss=0.f;
  #pragma unroll
  for (int ox=0;ox<7;ox++){ v[ox]=acc[ox]+bv; s+=v[ox]; ss+=v[ox]*v[ox]; }
  s_red[t]=s; s_red2[t]=ss;
  __syncthreads();
  if (t<4){
    float S=0.f, SS=0.f;
    for (int i=0;i<112;i++){ S+=s_red[112*t+i]; SS+=s_red2[112*t+i]; }
    float mean=S/784.f, var=SS/784.f-mean*mean;
    s_stats[t][0]=mean; s_stats[t][1]=rsqrtf(fmaxf(var,0.f)+1e-5f);
  }
  __syncthreads();
  float mean=s_stats[oc_l>>4][0], inv=s_stats[oc_l>>4][1];
  float ga=ldin(gamma, oc, isbf), be=ldin(beta, oc, isbf);
  __hip_bfloat16* op = out + ((size_t)b*CC+oc)*HW7 + row*7;
  #pragma unroll
  for (int ox=0;ox<7;ox++) op[ox] = f2bf(fmaxf((v[ox]-mean)*inv*ga+be, 0.f));
}

// ---- conv3x3 s1 p1 + GN(36) + ReLU; layer index passed for weight offsets --
__global__ __launch_bounds__(448) void conv3_gn_kernel(
    const __hip_bfloat16* __restrict__ in,
    const void* __restrict__ w,      // [7,576,576,9]; layer li
    const void* __restrict__ bias,   // [7,576]
    const void* __restrict__ gamma,  // [8,576]; row li+1
    const void* __restrict__ beta,
    const int* __restrict__ flagp, int li,
    __hip_bfloat16* __restrict__ out) {
  const int isbf = *flagp;
  const int b = blockIdx.x, ocb = blockIdx.y, t = threadIdx.x;
  const int oc_l = t / 7, row = t % 7;
  const int oc = ocb*64 + oc_l;
  const size_t wbase = (size_t)li*CC*CC*9;
  const size_t bbase = (size_t)li*CC;
  const size_t gbase = (size_t)(li+1)*CC;

  __shared__ float s_in[16][9][12];
  __shared__ float s_w[64*145];
  __shared__ float s_red[448], s_red2[448];
  __shared__ float s_stats[4][2];

  float acc[7]={0,0,0,0,0,0,0};
  for (int icc=0; icc<CC; icc+=16) {
    __syncthreads();
    for (int idx=t; idx<16*108; idx+=448) {
      int c = idx/108, rem = idx%108, r = rem/12, col = rem%12;
      int iy=r-1, ix=col-1;
      float v=0.f;
      if (iy>=0&&iy<7&&ix>=0&&ix<7) v = bf2f(in[((size_t)(b*CC + icc + c))*HW7 + iy*7+ix]);
      s_in[c][r][col]=v;
    }
    for (int idx=t; idx<64*144; idx+=448) {
      int o = idx/144, rem = idx%144;
      s_w[o*145+rem] = ldin(w, wbase + ((size_t)(ocb*64+o)*CC + icc + rem/9)*9 + rem%9, isbf);
    }
    __syncthreads();
    for (int c=0;c<16;c++){
      float wr[9];
      #pragma unroll
      for (int k=0;k<9;k++) wr[k]=s_w[oc_l*145 + c*9 + k];
      float R0[9],R1[9],R2[9];
      #pragma unroll
      for (int j=0;j<9;j++){R0[j]=s_in[c][row][j];R1[j]=s_in[c][row+1][j];R2[j]=s_in[c][row+2][j];}
      #pragma unroll
      for (int ox=0;ox<7;ox++){
        acc[ox] += R0[ox]*wr[0]+R0[ox+1]*wr[1]+R0[ox+2]*wr[2]
                 + R1[ox]*wr[3]+R1[ox+1]*wr[4]+R1[ox+2]*wr[5]
                 + R2[ox]*wr[6]+R2[ox+1]*wr[7]+R2[ox+2]*wr[8];
      }
    }
  }
  float bv=ldin(bias, bbase + oc, isbf);
  float v[7], s=0.f, ss=0.f;
  #pragma unroll
  for (int ox=0;ox<7;ox++){ v[ox]=acc[ox]+bv; s+=v[ox]; ss+=v[ox]*v[ox]; }
  s_red[t]=s; s_red2[t]=ss;
  __syncthreads();
  if (t<4){
    float S=0.f, SS=0.f;
    for (int i=0;i<112;i++){ S+=s_red[112*t+i]; SS+=s_red2[112*t+i]; }
    float mean=S/784.f, var=SS/784.f-mean*mean;
    s_stats[t][0]=mean; s_stats[t][1]=rsqrtf(fmaxf(var,0.f)+1e-5f);
  }
  __syncthreads();
  float mean=s_stats[oc_l>>4][0], inv=s_stats[oc_l>>4][1];
  float ga=ldin(gamma, gbase + oc, isbf), be=ldin(beta, gbase + oc, isbf);
  __hip_bfloat16* op = out + ((size_t)b*CC+oc)*HW7 + row*7;
  #pragma unroll
  for (int ox=0;ox<7;ox++) op[ox]=f2bf(fmaxf((v[ox]-mean)*inv*ga+be, 0.f));
}

// ---- edge message passing: out = base + sum_e pw(dw(src)) ----------------
__global__ __launch_bounds__(256) void edge_msg_kernel(
    const __hip_bfloat16* __restrict__ src_feat,
    const __hip_bfloat16* __restrict__ base,
    const void* __restrict__ dw_w,  // [24,64,25]
    const void* __restrict__ dw_b,  // [24,64]
    const void* __restrict__ pw_w,  // [24,64,64]
    const void* __restrict__ pw_b,  // [24,64]
    const int* __restrict__ flagp,
    __hip_bfloat16* __restrict__ out) {
  const int isbf = *flagp;
  const int b = blockIdx.x, dst = blockIdx.y, t = threadIdx.x;
  const int lc = t >> 2;
  const int q = t & 3;
  const int p0 = q*12 + (q?1:0);
  const int cnt = q? 12:13;

  __shared__ float s_pin[64][132];
  __shared__ float s_y[64][52];
  __shared__ __hip_bfloat16 s_pw[64][66];
  __shared__ float s_dw[64][26];

  float acc[13];
  #pragma unroll
  for (int i=0;i<13;i++) acc[i]=0.f;

  const int eoff = EDGE_OFF_C[dst];
  const int ecnt = EDGE_CNT_C[dst];
  for (int k=0;k<ecnt;k++) {
    const int e = eoff + k;
    const int src = EDGE_SRC_C[e];
    __syncthreads();
    const __hip_bfloat16* sp = src_feat + ((size_t)b*CC + src*SPC)*HW7;
    for (int idx=t; idx<64*132; idx+=256) {
      int c = idx/132, rem = idx%132, r = rem/12, col = rem%12;
      int iy=r-2, ix=col-2;
      float v=0.f;
      if (iy>=0&&iy<7&&ix>=0&&ix<7) v = bf2f(sp[c*HW7 + iy*7 + ix]);
      s_pin[c][rem]=v;
    }
    for (int idx=t; idx<64*25; idx+=256)
      s_dw[idx/25][idx%25] = ldin(dw_w, (size_t)e*1600 + idx, isbf);
    for (int idx=t; idx<64*64; idx+=256)
      s_pw[idx>>6][idx&63] = f2bf(ldin(pw_w, (size_t)e*4096 + idx, isbf));
    __syncthreads();
    {
      float dwb = ldin(dw_b, e*64 + lc, isbf);
      float wd[25];
      #pragma unroll
      for (int j=0;j<25;j++) wd[j]=s_dw[lc][j];
      for (int pi=0; pi<cnt; pi++) {
        int p = p0 + pi; int oy=p/7, ox=p-oy*7;
        float a = dwb;
        #pragma unroll
        for (int u=0;u<5;u++)
          #pragma unroll
          for (int vv=0;vv<5;vv++)
            a += s_pin[lc][(oy+u)*12 + ox+vv] * wd[u*5+vv];
        s_y[lc][p] = a;
      }
    }
    __syncthreads();
    {
      float pb = ldin(pw_b, e*64 + lc, isbf);
      for (int c=0;c<64;c++){
        float wv = bf2f(s_pw[lc][c]);
        #pragma unroll
        for (int pi=0;pi<13;pi++)
          if (pi<cnt) acc[pi] += s_y[c][p0+pi]*wv;
      }
      #pragma unroll
      for (int pi=0;pi<13;pi++) if (pi<cnt) acc[pi]+=pb;
    }
  }
  const size_t o0 = ((size_t)b*CC + dst*SPC + lc)*HW7;
  for (int pi=0;pi<cnt;pi++){
    int p=p0+pi;
    out[o0+p] = f2bf(bf2f(base[o0+p]) + acc[pi]);
  }
}

// ---- fused head: deconv1 + GN(9) + ReLU + deconv2 ------------------------
__global__ __launch_bounds__(256) void head_kernel(
    const __hip_bfloat16* __restrict__ in,     // [B,576,49] bf16 (internal)
    const void* __restrict__ w1,     // [576,64,16]
    const void* __restrict__ b1,     // [576]
    const void* __restrict__ gamma,  // [576]
    const void* __restrict__ beta,   // [576]
    const void* __restrict__ w2,     // [576,16]
    const void* __restrict__ b2,     // [9]
    const int* __restrict__ flagp,
    void* __restrict__ outp,         // external dtype
    size_t out_elem_off) {
  const int isbf = *flagp;
  const int b=blockIdx.x, g=blockIdx.y, t=threadIdx.x;
  const int o=t&63, q=t>>6;
  __shared__ float s_mid[64*196];
  __shared__ float s_w2[64][17];
  __shared__ float s_red[256], s_red2[256];
  __shared__ float s_stats[2];
  float* s_in = s_mid;  // alias; all s_in reads complete before s_mid writes

  for (int idx=t; idx<64*49; idx+=256)
    s_in[idx] = bf2f(in[((size_t)b*CC + g*SPC)*HW7 + idx]);
  for (int idx=t; idx<64*16; idx+=256)
    s_w2[idx>>4][idx&15] = ldin(w2, (g*SPC + (idx>>4))*16 + (idx&15), isbf);
  __syncthreads();

  float acc[4][14];
  #pragma unroll
  for (int r=0;r<4;r++)
    #pragma unroll
    for (int j=0;j<14;j++) acc[r][j]=0.f;

  for (int c=0;c<64;c++){
    const size_t w1o = ((size_t)(g*SPC+c)*64 + o)*16;
    float wr[16];
    #pragma unroll
    for (int k2=0;k2<16;k2++) wr[k2]=ldin(w1, w1o+k2, isbf);
    #pragma unroll
    for (int r=0;r<4;r++){
      int oy = q + 4*r;
      if (oy < 14) {
        #pragma unroll
        for (int kyi=0;kyi<2;kyi++){
          int ky = ((oy+1)&1) + 2*kyi;
          int ny = oy+1-ky;
          if (ny>=0) {
            int iy = ny>>1;
            if (iy<7) {
              #pragma unroll
              for (int ox=0;ox<14;ox++){
                #pragma unroll
                for (int kxi=0;kxi<2;kxi++){
                  int kx = ((ox+1)&1) + 2*kxi;
                  int nx = ox+1-kx;
                  if (nx>=0){
                    int ix=nx>>1;
                    if (ix<7) acc[r][ox] += s_in[c*49 + iy*7 + ix]*wr[ky*4+kx];
                  }
                }
              }
            }
          }
        }
      }
    }
  }
  float bv = ldin(b1, g*SPC+o, isbf);
  float s=0.f, ss=0.f;
  #pragma unroll
  for (int r=0;r<4;r++){
    int oy=q+4*r;
    if (oy<14){
      #pragma unroll
      for (int ox=0;ox<14;ox++){ float vv=acc[r][ox]+bv; acc[r][ox]=vv; s+=vv; ss+=vv*vv; }
    }
  }
  s_red[t]=s; s_red2[t]=ss;
  __syncthreads();
  if (t<64){ s_red[t]+=s_red[t+64]+s_red[t+128]+s_red[t+192];
             s_red2[t]+=s_red2[t+64]+s_red2[t+128]+s_red2[t+192]; }
  __syncthreads();
  if (t==0){
    float S=0.f, SS=0.f;
    for (int i=0;i<64;i++){ S+=s_red[i]; SS+=s_red2[i]; }
    float mean=S/12544.f, var=SS/12544.f-mean*mean;
    s_stats[0]=mean; s_stats[1]=rsqrtf(fmaxf(var,0.f)+1e-5f);
  }
  __syncthreads();
  float mean=s_stats[0], inv=s_stats[1];
  float ga=ldin(gamma, g*SPC+o, isbf), be=ldin(beta, g*SPC+o, isbf);
  #pragma unroll
  for (int r=0;r<4;r++){
    int oy=q+4*r;
    if (oy<14){
      #pragma unroll
      for (int ox=0;ox<14;ox++)
        s_mid[o*196 + oy*14 + ox] = fmaxf((acc[r][ox]-mean)*inv*ga+be, 0.f);
    }
  }
  __syncthreads();
  float b2v = ldin(b2, g, isbf);
  for (int p=t; p<HW28; p+=256) {
    int oy=p/28, ox=p-oy*28;
    float a = b2v;
    for (int c=0;c<64;c++) {
      #pragma unroll
      for (int kyi=0;kyi<2;kyi++){
        int ky=((oy+1)&1)+2*kyi; int ny=oy+1-ky;
        if (ny>=0){
          int iy=ny>>1;
          if (iy<14){
            #pragma unroll
            for (int kxi=0;kxi<2;kxi++){
              int kx=((ox+1)&1)+2*kxi; int nx=ox+1-kx;
              if (nx>=0){
                int ix=nx>>1;
                if (ix<14) a += s_mid[c*196+iy*14+ix]*s_w2[c][ky*4+kx];
              }
            }
          }
        }
      }
    }
    size_t oidx = out_elem_off + ((size_t)b*NGR+g)*HW28 + p;
    if (isbf) ((__hip_bfloat16*)outp)[oidx] = f2bf(a);
    else      ((float*)outp)[oidx] = a;
  }
}

extern "C" void kernel_launch(void* const* d_in, const int* in_sizes, int n_in,
                              void* d_out, int out_size, void* d_ws, size_t ws_size,
                              hipStream_t stream) {
  const void* x        = d_in[0];
  const void* convs_w0 = d_in[1];
  const void* convs_b0 = d_in[2];
  const void* convs_w  = d_in[3];
  const void* convs_b  = d_in[4];
  const void* gn_gamma = d_in[5];
  const void* gn_beta  = d_in[6];
  const void* fo_dw_w  = d_in[7];
  const void* fo_dw_b  = d_in[8];
  const void* fo_pw_w  = d_in[9];
  const void* fo_pw_b  = d_in[10];
  const void* so_dw_w  = d_in[11];
  const void* so_dw_b  = d_in[12];
  const void* so_pw_w  = d_in[13];
  const void* so_pw_b  = d_in[14];
  const void* up1_w    = d_in[15];
  const void* up1_b    = d_in[16];
  const void* sbn_g    = d_in[17];
  const void* sbn_b    = d_in[18];
  const void* up2_w    = d_in[19];
  const void* up2_b    = d_in[20];
  (void)in_sizes; (void)n_in; (void)out_size; (void)ws_size;

  // ws layout: [flag int, pad 16B][bufA][bufB][bufF], bf16 buffers of 1,806,336
  int* flag = (int*)d_ws;
  __hip_bfloat16* bufA = (__hip_bfloat16*)((char*)d_ws + 16);
  __hip_bfloat16* bufB = bufA + 1806336;
  __hip_bfloat16* bufF = bufB + 1806336;

  detect_kernel<<<1, 1, 0, stream>>>((const unsigned short*)x, flag);

  dim3 cgrid(BB, 9), cblk(448);
  conv0_gn_kernel<<<cgrid, cblk, 0, stream>>>(x, convs_w0, convs_b0, gn_gamma, gn_beta, flag, bufA);

  __hip_bfloat16* cur = bufA; __hip_bfloat16* nxt = bufB;
  for (int i=0;i<7;i++){
    conv3_gn_kernel<<<cgrid, cblk, 0, stream>>>(cur, convs_w, convs_b, gn_gamma, gn_beta, flag, i, nxt);
    __hip_bfloat16* tmp=cur; cur=nxt; nxt=tmp;
  }
  __hip_bfloat16* h = cur;        // bufB
  __hip_bfloat16* second = nxt;   // bufA (dead layer-6 output)

  edge_msg_kernel<<<dim3(BB,NGR), 256, 0, stream>>>(h,    h, fo_dw_w, fo_dw_b, fo_pw_w, fo_pw_b, flag, bufF);
  edge_msg_kernel<<<dim3(BB,NGR), 256, 0, stream>>>(bufF, h, so_dw_w, so_dw_b, so_pw_w, so_pw_b, flag, second);

  head_kernel<<<dim3(BB,NGR), 256, 0, stream>>>(h,      up1_w, up1_b, sbn_g, sbn_b, up2_w, up2_b, flag, d_out, 0);
  head_kernel<<<dim3(BB,NGR), 256, 0, stream>>>(second, up1_w, up1_b, sbn_g, sbn_b, up2_w, up2_b, flag, d_out, (size_t)BB*NGR*HW28);
}

// Round 4
// 2772.512 us; speedup vs baseline: 3.2596x; 3.2596x over previous
//
#include <hip/hip_runtime.h>
#include <hip/hip_bf16.h>

#define BB 64
#define CIN 256
#define CC 576
#define NGR 9
#define SPC 64
#define HW7 49
#define HW14 196
#define HW28 784

__device__ __constant__ int EDGE_SRC_C[24] = {1,3, 0,2,4, 1,5, 0,4,6, 1,3,5,7, 2,4,8, 3,7, 4,6,8, 5,7};
__device__ __constant__ int EDGE_OFF_C[9]  = {0,2,5,7,10,14,17,19,22};
__device__ __constant__ int EDGE_CNT_C[9]  = {2,3,2,3,4,3,2,3,2};

static __device__ __forceinline__ float bf2f(__hip_bfloat16 v){ return __bfloat162float(v); }
static __device__ __forceinline__ __hip_bfloat16 f2bf(float v){ return __float2bfloat16(v); }
static __device__ __forceinline__ float ldin(const void* p, size_t i, int isbf){
  return isbf ? bf2f(((const __hip_bfloat16*)p)[i]) : ((const float*)p)[i];
}

using bfrag = __attribute__((ext_vector_type(8))) short;
using f32x4 = __attribute__((ext_vector_type(4))) float;

// ---- dtype detector: classify x as bf16(1) or fp32(0) --------------------
__global__ void detect_kernel(const unsigned short* xs, int* flag) {
  if (threadIdx.x==0 && blockIdx.x==0) {
    int plaus = 0;
    for (int i=0;i<64;i++){
      unsigned short u = xs[2*i];
      int e = (u>>7)&0xFF;
      if (e>=100 && e<=140) plaus++;
    }
    *flag = (plaus >= 40) ? 1 : 0;
  }
}

// ---- x: [64,256,14,14] ext -> act0 NHWC bf16 [64][196][256] --------------
__global__ __launch_bounds__(256) void xcvt_kernel(
    const void* __restrict__ x, const int* __restrict__ flagp,
    __hip_bfloat16* __restrict__ act0) {
  const int b = blockIdx.x, icb = blockIdx.y, pxb = blockIdx.z, t = threadIdx.x;
  const int isbf = *flagp;
  __shared__ float lds[32][29];
  for (int idx=t; idx<32*28; idx+=256){
    int i = idx/28, j = idx - i*28;
    lds[i][j] = ldin(x, ((size_t)b*CIN + icb*32+i)*HW14 + pxb*28 + j, isbf);
  }
  __syncthreads();
  for (int idx=t; idx<28*32; idx+=256){
    int j = idx >> 5, i = idx & 31;
    act0[((size_t)b*HW14 + pxb*28 + j)*CIN + icb*32 + i] = f2bf(lds[i][j]);
  }
}

// ---- conv0 weights [576][256][9] ext -> [9][8][576][32] bf16 -------------
__global__ __launch_bounds__(256) void wcvt0_kernel(
    const void* __restrict__ w, const int* __restrict__ flagp,
    __hip_bfloat16* __restrict__ dst) {
  const int oc = blockIdx.x, t = threadIdx.x;
  const int isbf = *flagp;
  __shared__ float lds[2304];
  for (int idx=t; idx<2304; idx+=256)
    lds[idx] = ldin(w, (size_t)oc*2304 + idx, isbf);
  __syncthreads();
  for (int idx=t; idx<2304; idx+=256){
    int koff = idx >> 8, rem = idx & 255;
    int icb = rem >> 5, ici = rem & 31;
    dst[(((size_t)koff*8 + icb)*CC + oc)*32 + ici] = f2bf(lds[rem*9 + koff]);
  }
}

// ---- convs_w layer li [576][576][9] ext -> [9][18][576][32] bf16 ---------
__global__ __launch_bounds__(256) void wcvtL_kernel(
    const void* __restrict__ w, int li, const int* __restrict__ flagp,
    __hip_bfloat16* __restrict__ dst) {
  const int oc = blockIdx.x, t = threadIdx.x;
  const int isbf = *flagp;
  __shared__ float lds[5184];
  for (int idx=t; idx<5184; idx+=256)
    lds[idx] = ldin(w, ((size_t)li*CC + oc)*5184 + idx, isbf);
  __syncthreads();
  for (int idx=t; idx<5184; idx+=256){
    int koff = idx / 576, rem = idx - koff*576;
    int icb = rem >> 5, ici = rem & 31;
    dst[(((size_t)koff*18 + icb)*CC + oc)*32 + ici] = f2bf(lds[rem*9 + koff]);
  }
}

// ---- implicit-GEMM conv via MFMA: C[m=(b,p64)][n=oc] += A.B + bias -------
// A: NHWC bf16 act, Wb: [9][NICB][576][32] bf16. No LDS, no barriers.
template<int ICT, int NICB, int SW, int SH, int SPX, int STRIDE>
__global__ __launch_bounds__(256) void conv_mfma_kernel(
    const __hip_bfloat16* __restrict__ A,
    const __hip_bfloat16* __restrict__ Wb,
    const void* __restrict__ bias, int bias_off,
    const int* __restrict__ flagp,
    __hip_bfloat16* __restrict__ out) {     // NHWC [64][64][576]
  const int tid = threadIdx.x;
  const int l = tid & 63;
  const int w = tid >> 6;
  const int wm = w & 1, wn = w >> 1;
  const int mwb = blockIdx.x*64 + wm*32;
  const int nb  = blockIdx.y*64 + wn*32;
  const int ln = l & 15;
  const int icl = (l >> 4) * 8;

  int bidx[2], yy[2], xx[2]; bool pv[2];
  #pragma unroll
  for (int mf=0; mf<2; mf++){
    int m = mwb + mf*16 + ln;
    int b = m >> 6, p = m & 63;
    bidx[mf] = b; pv[mf] = (p < 49);
    yy[mf] = p/7; xx[mf] = p - yy[mf]*7;
  }

  f32x4 acc[2][2];
  #pragma unroll
  for (int i=0;i<2;i++)
    #pragma unroll
    for (int j=0;j<2;j++) acc[i][j] = (f32x4){0.f,0.f,0.f,0.f};

  const bfrag zf = {0,0,0,0,0,0,0,0};

  for (int koff=0; koff<9; koff++){
    const int dy = koff/3, dx = koff - dy*3;
    int arow[2]; bool val[2];
    #pragma unroll
    for (int mf=0; mf<2; mf++){
      int sy = yy[mf]*STRIDE + dy - 1;
      int sx = xx[mf]*STRIDE + dx - 1;
      val[mf] = pv[mf] && sy>=0 && sy<SH && sx>=0 && sx<SW;
      arow[mf] = (bidx[mf]*SPX + sy*SW + sx)*ICT + icl;
    }
    const int wko = koff*NICB;
    for (int icb=0; icb<NICB; icb++){
      bfrag a0 = val[0] ? *(const bfrag*)(A + arow[0] + icb*32) : zf;
      bfrag a1 = val[1] ? *(const bfrag*)(A + arow[1] + icb*32) : zf;
      const __hip_bfloat16* wp = Wb + (((size_t)(wko + icb)*CC + nb + ln)*32 + icl);
      bfrag b0 = *(const bfrag*)(wp);
      bfrag b1 = *(const bfrag*)(wp + 16*32);
      acc[0][0] = __builtin_amdgcn_mfma_f32_16x16x32_bf16(a0, b0, acc[0][0], 0,0,0);
      acc[1][0] = __builtin_amdgcn_mfma_f32_16x16x32_bf16(a1, b0, acc[1][0], 0,0,0);
      acc[0][1] = __builtin_amdgcn_mfma_f32_16x16x32_bf16(a0, b1, acc[0][1], 0,0,0);
      acc[1][1] = __builtin_amdgcn_mfma_f32_16x16x32_bf16(a1, b1, acc[1][1], 0,0,0);
    }
  }

  const int isbf = *flagp;
  const int quad = l >> 4;
  #pragma unroll
  for (int nf=0; nf<2; nf++){
    int n = nb + nf*16 + ln;
    float bv = ldin(bias, (size_t)bias_off + n, isbf);
    #pragma unroll
    for (int mf=0; mf<2; mf++){
      #pragma unroll
      for (int r=0; r<4; r++){
        int m = mwb + mf*16 + quad*4 + r;
        out[(size_t)m*CC + n] = f2bf(acc[mf][nf][r] + bv);
      }
    }
  }
}

// ---- GroupNorm(36)+ReLU on NHWC bf16 act, in place; only p<49 -----------
__global__ __launch_bounds__(256) void gn_nhwc_kernel(
    __hip_bfloat16* __restrict__ act,
    const void* __restrict__ gamma, const void* __restrict__ beta,
    int goff, const int* __restrict__ flagp) {
  const int b = blockIdx.x, g = blockIdx.y, t = threadIdx.x;
  const int ci = t & 15, pr = t >> 4;
  const int ch = g*16 + ci;
  float s=0.f, ss=0.f;
  for (int p=pr; p<49; p+=16){
    float v = bf2f(act[((size_t)b*64+p)*CC + ch]);
    s += v; ss += v*v;
  }
  #pragma unroll
  for (int o=32;o>0;o>>=1){ s+=__shfl_down(s,o); ss+=__shfl_down(ss,o); }
  __shared__ float red[8]; __shared__ float stats[2];
  int wid = t>>6;
  if ((t&63)==0){ red[wid]=s; red[4+wid]=ss; }
  __syncthreads();
  if (t==0){
    float S=red[0]+red[1]+red[2]+red[3];
    float SS=red[4]+red[5]+red[6]+red[7];
    float mean=S/784.f, var=SS/784.f-mean*mean;
    stats[0]=mean; stats[1]=rsqrtf(fmaxf(var,0.f)+1e-5f);
  }
  __syncthreads();
  const int isbf = *flagp;
  float mean=stats[0], inv=stats[1];
  float ga=ldin(gamma, (size_t)goff+ch, isbf), be=ldin(beta, (size_t)goff+ch, isbf);
  for (int p=pr; p<49; p+=16){
    size_t idx = ((size_t)b*64+p)*CC + ch;
    float v = (bf2f(act[idx])-mean)*inv*ga + be;
    act[idx] = f2bf(fmaxf(v, 0.f));
  }
}

// ---- NHWC [64][64][576] -> NCHW [64][576][49] bf16 ----------------------
__global__ __launch_bounds__(256) void nhwc2nchw_kernel(
    const __hip_bfloat16* __restrict__ src,
    __hip_bfloat16* __restrict__ dst) {
  const int b = blockIdx.x, cb = blockIdx.y, t = threadIdx.x;
  __shared__ float lds[49][33];
  for (int idx=t; idx<49*32; idx+=256){
    int p = idx >> 5, i = idx & 31;
    lds[p][i] = bf2f(src[((size_t)b*64+p)*CC + cb*32 + i]);
  }
  __syncthreads();
  for (int idx=t; idx<32*49; idx+=256){
    int c = idx/49, p = idx - c*49;
    dst[((size_t)b*CC + cb*32 + c)*HW7 + p] = f2bf(lds[p][c]);
  }
}

// ---- edge message passing: out = base + sum_e pw(dw(src)) (NCHW bf16) ----
__global__ __launch_bounds__(256) void edge_msg_kernel(
    const __hip_bfloat16* __restrict__ src_feat,
    const __hip_bfloat16* __restrict__ base,
    const void* __restrict__ dw_w,
    const void* __restrict__ dw_b,
    const void* __restrict__ pw_w,
    const void* __restrict__ pw_b,
    const int* __restrict__ flagp,
    __hip_bfloat16* __restrict__ out) {
  const int isbf = *flagp;
  const int b = blockIdx.x, dst = blockIdx.y, t = threadIdx.x;
  const int lc = t >> 2;
  const int q = t & 3;
  const int p0 = q*12 + (q?1:0);
  const int cnt = q? 12:13;

  __shared__ float s_pin[64][132];
  __shared__ float s_y[64][52];
  __shared__ __hip_bfloat16 s_pw[64][66];
  __shared__ float s_dw[64][26];

  float acc[13];
  #pragma unroll
  for (int i=0;i<13;i++) acc[i]=0.f;

  const int eoff = EDGE_OFF_C[dst];
  const int ecnt = EDGE_CNT_C[dst];
  for (int k=0;k<ecnt;k++) {
    const int e = eoff + k;
    const int src = EDGE_SRC_C[e];
    __syncthreads();
    const __hip_bfloat16* sp = src_feat + ((size_t)b*CC + src*SPC)*HW7;
    for (int idx=t; idx<64*132; idx+=256) {
      int c = idx/132, rem = idx%132, r = rem/12, col = rem%12;
      int iy=r-2, ix=col-2;
      float v=0.f;
      if (iy>=0&&iy<7&&ix>=0&&ix<7) v = bf2f(sp[c*HW7 + iy*7 + ix]);
      s_pin[c][rem]=v;
    }
    for (int idx=t; idx<64*25; idx+=256)
      s_dw[idx/25][idx%25] = ldin(dw_w, (size_t)e*1600 + idx, isbf);
    for (int idx=t; idx<64*64; idx+=256)
      s_pw[idx>>6][idx&63] = f2bf(ldin(pw_w, (size_t)e*4096 + idx, isbf));
    __syncthreads();
    {
      float dwb = ldin(dw_b, e*64 + lc, isbf);
      float wd[25];
      #pragma unroll
      for (int j=0;j<25;j++) wd[j]=s_dw[lc][j];
      for (int pi=0; pi<cnt; pi++) {
        int p = p0 + pi; int oy=p/7, ox=p-oy*7;
        float a = dwb;
        #pragma unroll
        for (int u=0;u<5;u++)
          #pragma unroll
          for (int vv=0;vv<5;vv++)
            a += s_pin[lc][(oy+u)*12 + ox+vv] * wd[u*5+vv];
        s_y[lc][p] = a;
      }
    }
    __syncthreads();
    {
      float pb = ldin(pw_b, e*64 + lc, isbf);
      for (int c=0;c<64;c++){
        float wv = bf2f(s_pw[lc][c]);
        #pragma unroll
        for (int pi=0;pi<13;pi++)
          if (pi<cnt) acc[pi] += s_y[c][p0+pi]*wv;
      }
      #pragma unroll
      for (int pi=0;pi<13;pi++) if (pi<cnt) acc[pi]+=pb;
    }
  }
  const size_t o0 = ((size_t)b*CC + dst*SPC + lc)*HW7;
  for (int pi=0;pi<cnt;pi++){
    int p=p0+pi;
    out[o0+p] = f2bf(bf2f(base[o0+p]) + acc[pi]);
  }
}

// ---- fused head: deconv1 + GN(9) + ReLU + deconv2 ------------------------
__global__ __launch_bounds__(256) void head_kernel(
    const __hip_bfloat16* __restrict__ in,     // [B,576,49] bf16
    const void* __restrict__ w1,
    const void* __restrict__ b1,
    const void* __restrict__ gamma,
    const void* __restrict__ beta,
    const void* __restrict__ w2,
    const void* __restrict__ b2,
    const int* __restrict__ flagp,
    void* __restrict__ outp,
    size_t out_elem_off) {
  const int isbf = *flagp;
  const int b=blockIdx.x, g=blockIdx.y, t=threadIdx.x;
  const int o=t&63, q=t>>6;
  __shared__ float s_mid[64*196];
  __shared__ float s_w2[64][17];
  __shared__ float s_red[256], s_red2[256];
  __shared__ float s_stats[2];
  float* s_in = s_mid;

  for (int idx=t; idx<64*49; idx+=256)
    s_in[idx] = bf2f(in[((size_t)b*CC + g*SPC)*HW7 + idx]);
  for (int idx=t; idx<64*16; idx+=256)
    s_w2[idx>>4][idx&15] = ldin(w2, (g*SPC + (idx>>4))*16 + (idx&15), isbf);
  __syncthreads();

  float acc[4][14];
  #pragma unroll
  for (int r=0;r<4;r++)
    #pragma unroll
    for (int j=0;j<14;j++) acc[r][j]=0.f;

  for (int c=0;c<64;c++){
    const size_t w1o = ((size_t)(g*SPC+c)*64 + o)*16;
    float wr[16];
    #pragma unroll
    for (int k2=0;k2<16;k2++) wr[k2]=ldin(w1, w1o+k2, isbf);
    #pragma unroll
    for (int r=0;r<4;r++){
      int oy = q + 4*r;
      if (oy < 14) {
        #pragma unroll
        for (int kyi=0;kyi<2;kyi++){
          int ky = ((oy+1)&1) + 2*kyi;
          int ny = oy+1-ky;
          if (ny>=0) {
            int iy = ny>>1;
            if (iy<7) {
              #pragma unroll
              for (int ox=0;ox<14;ox++){
                #pragma unroll
                for (int kxi=0;kxi<2;kxi++){
                  int kx = ((ox+1)&1) + 2*kxi;
                  int nx = ox+1-kx;
                  if (nx>=0){
                    int ix=nx>>1;
                    if (ix<7) acc[r][ox] += s_in[c*49 + iy*7 + ix]*wr[ky*4+kx];
                  }
                }
              }
            }
          }
        }
      }
    }
  }
  float bv = ldin(b1, g*SPC+o, isbf);
  float s=0.f, ss=0.f;
  #pragma unroll
  for (int r=0;r<4;r++){
    int oy=q+4*r;
    if (oy<14){
      #pragma unroll
      for (int ox=0;ox<14;ox++){ float vv=acc[r][ox]+bv; acc[r][ox]=vv; s+=vv; ss+=vv*vv; }
    }
  }
  s_red[t]=s; s_red2[t]=ss;
  __syncthreads();
  if (t<64){ s_red[t]+=s_red[t+64]+s_red[t+128]+s_red[t+192];
             s_red2[t]+=s_red2[t+64]+s_red2[t+128]+s_red2[t+192]; }
  __syncthreads();
  if (t==0){
    float S=0.f, SS=0.f;
    for (int i=0;i<64;i++){ S+=s_red[i]; SS+=s_red2[i]; }
    float mean=S/12544.f, var=SS/12544.f-mean*mean;
    s_stats[0]=mean; s_stats[1]=rsqrtf(fmaxf(var,0.f)+1e-5f);
  }
  __syncthreads();
  float mean=s_stats[0], inv=s_stats[1];
  float ga=ldin(gamma, g*SPC+o, isbf), be=ldin(beta, g*SPC+o, isbf);
  #pragma unroll
  for (int r=0;r<4;r++){
    int oy=q+4*r;
    if (oy<14){
      #pragma unroll
      for (int ox=0;ox<14;ox++)
        s_mid[o*196 + oy*14 + ox] = fmaxf((acc[r][ox]-mean)*inv*ga+be, 0.f);
    }
  }
  __syncthreads();
  float b2v = ldin(b2, g, isbf);
  for (int p=t; p<HW28; p+=256) {
    int oy=p/28, ox=p-oy*28;
    float a = b2v;
    for (int c=0;c<64;c++) {
      #pragma unroll
      for (int kyi=0;kyi<2;kyi++){
        int ky=((oy+1)&1)+2*kyi; int ny=oy+1-ky;
        if (ny>=0){
          int iy=ny>>1;
          if (iy<14){
            #pragma unroll
            for (int kxi=0;kxi<2;kxi++){
              int kx=((ox+1)&1)+2*kxi; int nx=ox+1-kx;
              if (nx>=0){
                int ix=nx>>1;
                if (ix<14) a += s_mid[c*196+iy*14+ix]*s_w2[c][ky*4+kx];
              }
            }
          }
        }
      }
    }
    size_t oidx = out_elem_off + ((size_t)b*NGR+g)*HW28 + p;
    if (isbf) ((__hip_bfloat16*)outp)[oidx] = f2bf(a);
    else      ((float*)outp)[oidx] = a;
  }
}

extern "C" void kernel_launch(void* const* d_in, const int* in_sizes, int n_in,
                              void* d_out, int out_size, void* d_ws, size_t ws_size,
                              hipStream_t stream) {
  const void* x        = d_in[0];
  const void* convs_w0 = d_in[1];
  const void* convs_b0 = d_in[2];
  const void* convs_w  = d_in[3];
  const void* convs_b  = d_in[4];
  const void* gn_gamma = d_in[5];
  const void* gn_beta  = d_in[6];
  const void* fo_dw_w  = d_in[7];
  const void* fo_dw_b  = d_in[8];
  const void* fo_pw_w  = d_in[9];
  const void* fo_pw_b  = d_in[10];
  const void* so_dw_w  = d_in[11];
  const void* so_dw_b  = d_in[12];
  const void* so_pw_w  = d_in[13];
  const void* so_pw_b  = d_in[14];
  const void* up1_w    = d_in[15];
  const void* up1_b    = d_in[16];
  const void* sbn_g    = d_in[17];
  const void* sbn_b    = d_in[18];
  const void* up2_w    = d_in[19];
  const void* up2_b    = d_in[20];
  (void)in_sizes; (void)n_in; (void)out_size; (void)ws_size;

  // ws layout (bytes): flag 16 | act0 6.42M | actA 4.72M | actB 4.72M |
  //                    wbuf 5.97M | h_nchw 3.61M | bufF 3.61M | second 3.61M
  int* flag = (int*)d_ws;
  char* wsb = (char*)d_ws + 16;
  __hip_bfloat16* act0   = (__hip_bfloat16*)(wsb);
  __hip_bfloat16* actA   = (__hip_bfloat16*)(wsb + 6422528);
  __hip_bfloat16* actB   = (__hip_bfloat16*)(wsb + 6422528 + 4718592);
  __hip_bfloat16* wbuf   = (__hip_bfloat16*)(wsb + 6422528 + 2*4718592);
  __hip_bfloat16* h_nchw = (__hip_bfloat16*)(wsb + 6422528 + 2*4718592 + 5971968);
  __hip_bfloat16* bufF   = h_nchw + 1806336;
  __hip_bfloat16* second = bufF + 1806336;

  detect_kernel<<<1, 1, 0, stream>>>((const unsigned short*)x, flag);

  xcvt_kernel<<<dim3(BB,8,7), 256, 0, stream>>>(x, flag, act0);
  wcvt0_kernel<<<CC, 256, 0, stream>>>(convs_w0, flag, wbuf);
  conv_mfma_kernel<256,8,14,14,196,2><<<dim3(64,9), 256, 0, stream>>>(
      act0, wbuf, convs_b0, 0, flag, actA);
  gn_nhwc_kernel<<<dim3(BB,36), 256, 0, stream>>>(actA, gn_gamma, gn_beta, 0, flag);

  __hip_bfloat16* cur = actA; __hip_bfloat16* nxt = actB;
  for (int i=0;i<7;i++){
    wcvtL_kernel<<<CC, 256, 0, stream>>>(convs_w, i, flag, wbuf);
    conv_mfma_kernel<576,18,7,7,64,1><<<dim3(64,9), 256, 0, stream>>>(
        cur, wbuf, convs_b, i*CC, flag, nxt);
    gn_nhwc_kernel<<<dim3(BB,36), 256, 0, stream>>>(nxt, gn_gamma, gn_beta, (i+1)*CC, flag);
    __hip_bfloat16* tmp=cur; cur=nxt; nxt=tmp;
  }

  nhwc2nchw_kernel<<<dim3(BB,18), 256, 0, stream>>>(cur, h_nchw);

  edge_msg_kernel<<<dim3(BB,NGR), 256, 0, stream>>>(h_nchw, h_nchw, fo_dw_w, fo_dw_b, fo_pw_w, fo_pw_b, flag, bufF);
  edge_msg_kernel<<<dim3(BB,NGR), 256, 0, stream>>>(bufF, h_nchw, so_dw_w, so_dw_b, so_pw_w, so_pw_b, flag, second);

  head_kernel<<<dim3(BB,NGR), 256, 0, stream>>>(h_nchw, up1_w, up1_b, sbn_g, sbn_b, up2_w, up2_b, flag, d_out, 0);
  head_kernel<<<dim3(BB,NGR), 256, 0, stream>>>(second, up1_w, up1_b, sbn_g, sbn_b, up2_w, up2_b, flag, d_out, (size_t)BB*NGR*HW28);
}

// Round 5
// 1911.265 us; speedup vs baseline: 4.7284x; 1.4506x over previous
//
#include <hip/hip_runtime.h>
#include <hip/hip_bf16.h>

#define BB 64
#define CIN 256
#define CC 576
#define NGR 9
#define SPC 64
#define HW7 49
#define HW14 196
#define HW28 784

__device__ __constant__ int EDGE_SRC_C[24] = {1,3, 0,2,4, 1,5, 0,4,6, 1,3,5,7, 2,4,8, 3,7, 4,6,8, 5,7};
__device__ __constant__ int EDGE_OFF_C[9]  = {0,2,5,7,10,14,17,19,22};
__device__ __constant__ int EDGE_CNT_C[9]  = {2,3,2,3,4,3,2,3,2};

static __device__ __forceinline__ float bf2f(__hip_bfloat16 v){ return __bfloat162float(v); }
static __device__ __forceinline__ __hip_bfloat16 f2bf(float v){ return __float2bfloat16(v); }
static __device__ __forceinline__ float ldin(const void* p, size_t i, int isbf){
  return isbf ? bf2f(((const __hip_bfloat16*)p)[i]) : ((const float*)p)[i];
}

using bfrag = __attribute__((ext_vector_type(8))) short;
using f32x4 = __attribute__((ext_vector_type(4))) float;

// ---- dtype detector ------------------------------------------------------
__global__ void detect_kernel(const unsigned short* xs, int* flag) {
  if (threadIdx.x==0 && blockIdx.x==0) {
    int plaus = 0;
    for (int i=0;i<64;i++){
      unsigned short u = xs[2*i];
      int e = (u>>7)&0xFF;
      if (e>=100 && e<=140) plaus++;
    }
    *flag = (plaus >= 40) ? 1 : 0;
  }
}

// ---- x: [64,256,14,14] ext -> act0 NHWC bf16 [64][196][256] --------------
__global__ __launch_bounds__(256) void xcvt_kernel(
    const void* __restrict__ x, const int* __restrict__ flagp,
    __hip_bfloat16* __restrict__ act0) {
  const int b = blockIdx.x, icb = blockIdx.y, pxb = blockIdx.z, t = threadIdx.x;
  const int isbf = *flagp;
  __shared__ float lds[32][29];
  for (int idx=t; idx<32*28; idx+=256){
    int i = idx/28, j = idx - i*28;
    lds[i][j] = ldin(x, ((size_t)b*CIN + icb*32+i)*HW14 + pxb*28 + j, isbf);
  }
  __syncthreads();
  for (int idx=t; idx<28*32; idx+=256){
    int j = idx >> 5, i = idx & 31;
    act0[((size_t)b*HW14 + pxb*28 + j)*CIN + icb*32 + i] = f2bf(lds[i][j]);
  }
}

// ---- conv0 weights [576][256][9] ext -> [9][8][576][32] bf16 -------------
__global__ __launch_bounds__(256) void wcvt0_kernel(
    const void* __restrict__ w, const int* __restrict__ flagp,
    __hip_bfloat16* __restrict__ dst) {
  const int oc = blockIdx.x, t = threadIdx.x;
  const int isbf = *flagp;
  __shared__ float lds[2304];
  for (int idx=t; idx<2304; idx+=256)
    lds[idx] = ldin(w, (size_t)oc*2304 + idx, isbf);
  __syncthreads();
  for (int idx=t; idx<2304; idx+=256){
    int koff = idx >> 8, rem = idx & 255;
    int icb = rem >> 5, ici = rem & 31;
    dst[(((size_t)koff*8 + icb)*CC + oc)*32 + ici] = f2bf(lds[rem*9 + koff]);
  }
}

// ---- convs_w layer li [576][576][9] ext -> [9][18][576][32] bf16 ---------
__global__ __launch_bounds__(256) void wcvtL_kernel(
    const void* __restrict__ w, int li, const int* __restrict__ flagp,
    __hip_bfloat16* __restrict__ dst) {
  const int oc = blockIdx.x, t = threadIdx.x;
  const int isbf = *flagp;
  __shared__ float lds[5184];
  for (int idx=t; idx<5184; idx+=256)
    lds[idx] = ldin(w, ((size_t)li*CC + oc)*5184 + idx, isbf);
  __syncthreads();
  for (int idx=t; idx<5184; idx+=256){
    int koff = idx / 576, rem = idx - koff*576;
    int icb = rem >> 5, ici = rem & 31;
    dst[(((size_t)koff*18 + icb)*CC + oc)*32 + ici] = f2bf(lds[rem*9 + koff]);
  }
}

// ---- implicit-GEMM conv via MFMA (unchanged, validated) ------------------
template<int ICT, int NICB, int SW, int SH, int SPX, int STRIDE>
__global__ __launch_bounds__(256) void conv_mfma_kernel(
    const __hip_bfloat16* __restrict__ A,
    const __hip_bfloat16* __restrict__ Wb,
    const void* __restrict__ bias, int bias_off,
    const int* __restrict__ flagp,
    __hip_bfloat16* __restrict__ out) {
  const int tid = threadIdx.x;
  const int l = tid & 63;
  const int w = tid >> 6;
  const int wm = w & 1, wn = w >> 1;
  const int mwb = blockIdx.x*64 + wm*32;
  const int nb  = blockIdx.y*64 + wn*32;
  const int ln = l & 15;
  const int icl = (l >> 4) * 8;

  int bidx[2], yy[2], xx[2]; bool pv[2];
  #pragma unroll
  for (int mf=0; mf<2; mf++){
    int m = mwb + mf*16 + ln;
    int b = m >> 6, p = m & 63;
    bidx[mf] = b; pv[mf] = (p < 49);
    yy[mf] = p/7; xx[mf] = p - yy[mf]*7;
  }

  f32x4 acc[2][2];
  #pragma unroll
  for (int i=0;i<2;i++)
    #pragma unroll
    for (int j=0;j<2;j++) acc[i][j] = (f32x4){0.f,0.f,0.f,0.f};

  const bfrag zf = {0,0,0,0,0,0,0,0};

  for (int koff=0; koff<9; koff++){
    const int dy = koff/3, dx = koff - dy*3;
    int arow[2]; bool val[2];
    #pragma unroll
    for (int mf=0; mf<2; mf++){
      int sy = yy[mf]*STRIDE + dy - 1;
      int sx = xx[mf]*STRIDE + dx - 1;
      val[mf] = pv[mf] && sy>=0 && sy<SH && sx>=0 && sx<SW;
      arow[mf] = (bidx[mf]*SPX + sy*SW + sx)*ICT + icl;
    }
    const int wko = koff*NICB;
    for (int icb=0; icb<NICB; icb++){
      bfrag a0 = val[0] ? *(const bfrag*)(A + arow[0] + icb*32) : zf;
      bfrag a1 = val[1] ? *(const bfrag*)(A + arow[1] + icb*32) : zf;
      const __hip_bfloat16* wp = Wb + (((size_t)(wko + icb)*CC + nb + ln)*32 + icl);
      bfrag b0 = *(const bfrag*)(wp);
      bfrag b1 = *(const bfrag*)(wp + 16*32);
      acc[0][0] = __builtin_amdgcn_mfma_f32_16x16x32_bf16(a0, b0, acc[0][0], 0,0,0);
      acc[1][0] = __builtin_amdgcn_mfma_f32_16x16x32_bf16(a1, b0, acc[1][0], 0,0,0);
      acc[0][1] = __builtin_amdgcn_mfma_f32_16x16x32_bf16(a0, b1, acc[0][1], 0,0,0);
      acc[1][1] = __builtin_amdgcn_mfma_f32_16x16x32_bf16(a1, b1, acc[1][1], 0,0,0);
    }
  }

  const int isbf = *flagp;
  const int quad = l >> 4;
  #pragma unroll
  for (int nf=0; nf<2; nf++){
    int n = nb + nf*16 + ln;
    float bv = ldin(bias, (size_t)bias_off + n, isbf);
    #pragma unroll
    for (int mf=0; mf<2; mf++){
      #pragma unroll
      for (int r=0; r<4; r++){
        int m = mwb + mf*16 + quad*4 + r;
        out[(size_t)m*CC + n] = f2bf(acc[mf][nf][r] + bv);
      }
    }
  }
}

// ---- GroupNorm(36)+ReLU on NHWC act [64][64][576], p<49 ------------------
__global__ __launch_bounds__(256) void gn_nhwc_kernel(
    __hip_bfloat16* __restrict__ act,
    const void* __restrict__ gamma, const void* __restrict__ beta,
    int goff, const int* __restrict__ flagp) {
  const int b = blockIdx.x, g = blockIdx.y, t = threadIdx.x;
  const int ci = t & 15, pr = t >> 4;
  const int ch = g*16 + ci;
  float s=0.f, ss=0.f;
  for (int p=pr; p<49; p+=16){
    float v = bf2f(act[((size_t)b*64+p)*CC + ch]);
    s += v; ss += v*v;
  }
  #pragma unroll
  for (int o=32;o>0;o>>=1){ s+=__shfl_down(s,o); ss+=__shfl_down(ss,o); }
  __shared__ float red[8]; __shared__ float stats[2];
  int wid = t>>6;
  if ((t&63)==0){ red[wid]=s; red[4+wid]=ss; }
  __syncthreads();
  if (t==0){
    float S=red[0]+red[1]+red[2]+red[3];
    float SS=red[4]+red[5]+red[6]+red[7];
    float mean=S/784.f, var=SS/784.f-mean*mean;
    stats[0]=mean; stats[1]=rsqrtf(fmaxf(var,0.f)+1e-5f);
  }
  __syncthreads();
  const int isbf = *flagp;
  float mean=stats[0], inv=stats[1];
  float ga=ldin(gamma, (size_t)goff+ch, isbf), be=ldin(beta, (size_t)goff+ch, isbf);
  for (int p=pr; p<49; p+=16){
    size_t idx = ((size_t)b*64+p)*CC + ch;
    float v = (bf2f(act[idx])-mean)*inv*ga + be;
    act[idx] = f2bf(fmaxf(v, 0.f));
  }
}

// ---- NHWC [64][64][576] -> NCHW [64][576][49] bf16 ----------------------
__global__ __launch_bounds__(256) void nhwc2nchw_kernel(
    const __hip_bfloat16* __restrict__ src,
    __hip_bfloat16* __restrict__ dst) {
  const int b = blockIdx.x, cb = blockIdx.y, t = threadIdx.x;
  __shared__ float lds[49][33];
  for (int idx=t; idx<49*32; idx+=256){
    int p = idx >> 5, i = idx & 31;
    lds[p][i] = bf2f(src[((size_t)b*64+p)*CC + cb*32 + i]);
  }
  __syncthreads();
  for (int idx=t; idx<32*49; idx+=256){
    int c = idx/49, p = idx - c*49;
    dst[((size_t)b*CC + cb*32 + c)*HW7 + p] = f2bf(lds[p][c]);
  }
}

// ---- edge message passing (NCHW in); out NCHW or NHWC --------------------
__global__ __launch_bounds__(256) void edge_msg_kernel(
    const __hip_bfloat16* __restrict__ src_feat,
    const __hip_bfloat16* __restrict__ base,
    const void* __restrict__ dw_w,
    const void* __restrict__ dw_b,
    const void* __restrict__ pw_w,
    const void* __restrict__ pw_b,
    const int* __restrict__ flagp, int out_nhwc,
    __hip_bfloat16* __restrict__ out) {
  const int isbf = *flagp;
  const int b = blockIdx.x, dst = blockIdx.y, t = threadIdx.x;
  const int lc = t >> 2;
  const int q = t & 3;
  const int p0 = q*12 + (q?1:0);
  const int cnt = q? 12:13;

  __shared__ float s_pin[64][132];
  __shared__ float s_y[64][52];
  __shared__ __hip_bfloat16 s_pw[64][66];
  __shared__ float s_dw[64][26];

  float acc[13];
  #pragma unroll
  for (int i=0;i<13;i++) acc[i]=0.f;

  const int eoff = EDGE_OFF_C[dst];
  const int ecnt = EDGE_CNT_C[dst];
  for (int k=0;k<ecnt;k++) {
    const int e = eoff + k;
    const int src = EDGE_SRC_C[e];
    __syncthreads();
    const __hip_bfloat16* sp = src_feat + ((size_t)b*CC + src*SPC)*HW7;
    for (int idx=t; idx<64*132; idx+=256) {
      int c = idx/132, rem = idx%132, r = rem/12, col = rem%12;
      int iy=r-2, ix=col-2;
      float v=0.f;
      if (iy>=0&&iy<7&&ix>=0&&ix<7) v = bf2f(sp[c*HW7 + iy*7 + ix]);
      s_pin[c][rem]=v;
    }
    for (int idx=t; idx<64*25; idx+=256)
      s_dw[idx/25][idx%25] = ldin(dw_w, (size_t)e*1600 + idx, isbf);
    for (int idx=t; idx<64*64; idx+=256)
      s_pw[idx>>6][idx&63] = f2bf(ldin(pw_w, (size_t)e*4096 + idx, isbf));
    __syncthreads();
    {
      float dwb = ldin(dw_b, e*64 + lc, isbf);
      float wd[25];
      #pragma unroll
      for (int j=0;j<25;j++) wd[j]=s_dw[lc][j];
      for (int pi=0; pi<cnt; pi++) {
        int p = p0 + pi; int oy=p/7, ox=p-oy*7;
        float a = dwb;
        #pragma unroll
        for (int u=0;u<5;u++)
          #pragma unroll
          for (int vv=0;vv<5;vv++)
            a += s_pin[lc][(oy+u)*12 + ox+vv] * wd[u*5+vv];
        s_y[lc][p] = a;
      }
    }
    __syncthreads();
    {
      float pb = ldin(pw_b, e*64 + lc, isbf);
      for (int c=0;c<64;c++){
        float wv = bf2f(s_pw[lc][c]);
        #pragma unroll
        for (int pi=0;pi<13;pi++)
          if (pi<cnt) acc[pi] += s_y[c][p0+pi]*wv;
      }
      #pragma unroll
      for (int pi=0;pi<13;pi++) if (pi<cnt) acc[pi]+=pb;
    }
  }
  const size_t o0 = ((size_t)b*CC + dst*SPC + lc)*HW7;
  for (int pi=0;pi<cnt;pi++){
    int p=p0+pi;
    float val = bf2f(base[o0+p]) + acc[pi];
    if (out_nhwc) out[((size_t)b*64 + p)*CC + dst*SPC + lc] = f2bf(val);
    else          out[o0+p] = f2bf(val);
  }
}

// ---- up1_w [576][64][16] ext -> wpack [9][16tap][64oc][64ic] bf16 --------
__global__ __launch_bounds__(256) void wpack_dc1_kernel(
    const void* __restrict__ w1, const int* __restrict__ flagp,
    __hip_bfloat16* __restrict__ dst) {
  const int gtap = blockIdx.x, t = threadIdx.x;
  const int isbf = *flagp;
  const int g = gtap >> 4, tap = gtap & 15;
  for (int idx=t; idx<64*64; idx+=256){
    int oc = idx >> 6, ic = idx & 63;
    dst[((size_t)gtap*64 + oc)*64 + ic] =
        f2bf(ldin(w1, ((size_t)(g*64+ic)*64 + oc)*16 + tap, isbf));
  }
}

// ---- deconv1 via MFMA: H NHWC [64][64][576] -> mid NHWC [64][196][576] ---
// per group g: M=(b,196px)=12544, N=64 oc, K=16 taps x 64 ic (masked)
__global__ __launch_bounds__(256) void dc1_mfma_kernel(
    const __hip_bfloat16* __restrict__ H,
    const __hip_bfloat16* __restrict__ Wp,   // [g*16+tap][oc][ic]
    const void* __restrict__ b1,
    const int* __restrict__ flagp,
    __hip_bfloat16* __restrict__ mid) {
  const int tid = threadIdx.x;
  const int l = tid & 63;
  const int w = tid >> 6;
  const int wm = w & 1, wn = w >> 1;
  const int g = blockIdx.y;
  const int mt = blockIdx.x*64 + wm*32;
  const int nb = wn*32;
  const int ln = l & 15;
  const int quad = l >> 4;

  int bb[2], iy_t[2][4], ix_t[2][4]; bool vy[2][4], vx[2][4];
  #pragma unroll
  for (int mf=0; mf<2; mf++){
    int m = mt + mf*16 + ln;
    int b = m/196, px = m - b*196;
    bb[mf] = b;
    int oy = px/14, ox = px - oy*14;
    #pragma unroll
    for (int k=0;k<4;k++){
      int ny = oy+1-k; vy[mf][k] = (ny>=0) && !(ny&1) && (ny>>1)<7; iy_t[mf][k]=(ny>>1)*7;
      int nx = ox+1-k; vx[mf][k] = (nx>=0) && !(nx&1) && (nx>>1)<7; ix_t[mf][k]=nx>>1;
    }
  }

  f32x4 acc[2][2];
  #pragma unroll
  for (int i=0;i<2;i++)
    #pragma unroll
    for (int j=0;j<2;j++) acc[i][j] = (f32x4){0.f,0.f,0.f,0.f};
  const bfrag zf = {0,0,0,0,0,0,0,0};

  for (int tap=0; tap<16; tap++){
    const int ky = tap>>2, kx = tap&3;
    int ipx[2]; bool tv[2];
    #pragma unroll
    for (int mf=0; mf<2; mf++){
      tv[mf] = vy[mf][ky] && vx[mf][kx];
      ipx[mf] = iy_t[mf][ky] + ix_t[mf][kx];
    }
    const __hip_bfloat16* wrow = Wp + (((size_t)(g*16+tap)*64 + nb + ln)*64);
    #pragma unroll
    for (int half=0; half<2; half++){
      const int icq = half*32 + quad*8;
      bfrag a0 = tv[0] ? *(const bfrag*)(H + ((size_t)(bb[0]*64 + ipx[0]))*CC + g*64 + icq) : zf;
      bfrag a1 = tv[1] ? *(const bfrag*)(H + ((size_t)(bb[1]*64 + ipx[1]))*CC + g*64 + icq) : zf;
      bfrag b0 = *(const bfrag*)(wrow + icq);
      bfrag b1v = *(const bfrag*)(wrow + 16*64 + icq);
      acc[0][0] = __builtin_amdgcn_mfma_f32_16x16x32_bf16(a0, b0,  acc[0][0], 0,0,0);
      acc[1][0] = __builtin_amdgcn_mfma_f32_16x16x32_bf16(a1, b0,  acc[1][0], 0,0,0);
      acc[0][1] = __builtin_amdgcn_mfma_f32_16x16x32_bf16(a0, b1v, acc[0][1], 0,0,0);
      acc[1][1] = __builtin_amdgcn_mfma_f32_16x16x32_bf16(a1, b1v, acc[1][1], 0,0,0);
    }
  }

  const int isbf = *flagp;
  #pragma unroll
  for (int nf=0; nf<2; nf++){
    int n = g*64 + nb + nf*16 + ln;
    float bv = ldin(b1, n, isbf);
    #pragma unroll
    for (int mf=0; mf<2; mf++){
      #pragma unroll
      for (int r=0; r<4; r++){
        int m = mt + mf*16 + quad*4 + r;
        int b = m/196, px = m - b*196;
        mid[((size_t)b*196 + px)*CC + n] = f2bf(acc[mf][nf][r] + bv);
      }
    }
  }
}

// ---- GN(9 groups: 64ch x 196px) + ReLU on mid NHWC, in place -------------
__global__ __launch_bounds__(256) void gn9_nhwc_kernel(
    __hip_bfloat16* __restrict__ mid,
    const void* __restrict__ gamma, const void* __restrict__ beta,
    const int* __restrict__ flagp) {
  const int b = blockIdx.x, g = blockIdx.y, t = threadIdx.x;
  const int ci = t & 63;
  float s=0.f, ss=0.f;
  for (int i=t; i<12544; i+=256){
    int px = i >> 6;
    float v = bf2f(mid[((size_t)b*196+px)*CC + g*64 + ci]);
    s += v; ss += v*v;
  }
  #pragma unroll
  for (int o=32;o>0;o>>=1){ s+=__shfl_down(s,o); ss+=__shfl_down(ss,o); }
  __shared__ float red[8]; __shared__ float stats[2];
  int wid = t>>6;
  if ((t&63)==0){ red[wid]=s; red[4+wid]=ss; }
  __syncthreads();
  if (t==0){
    float S=red[0]+red[1]+red[2]+red[3];
    float SS=red[4]+red[5]+red[6]+red[7];
    float mean=S/12544.f, var=SS/12544.f-mean*mean;
    stats[0]=mean; stats[1]=rsqrtf(fmaxf(var,0.f)+1e-5f);
  }
  __syncthreads();
  const int isbf = *flagp;
  float mean=stats[0], inv=stats[1];
  float ga=ldin(gamma, g*64+ci, isbf), be=ldin(beta, g*64+ci, isbf);
  for (int i=t; i<12544; i+=256){
    int px = i >> 6;
    size_t idx = ((size_t)b*196+px)*CC + g*64 + ci;
    float v = (bf2f(mid[idx])-mean)*inv*ga + be;
    mid[idx] = f2bf(fmaxf(v, 0.f));
  }
}

// ---- deconv2 from mid NHWC: [64ic x 196px] -> 1ch 28x28 per (b,g) --------
__global__ __launch_bounds__(256) void dc2_nhwc_kernel(
    const __hip_bfloat16* __restrict__ mid,
    const void* __restrict__ w2,
    const void* __restrict__ b2,
    const int* __restrict__ flagp,
    void* __restrict__ outp,
    size_t out_elem_off) {
  const int isbf = *flagp;
  const int b=blockIdx.x, g=blockIdx.y, t=threadIdx.x;
  __shared__ float s_mid[64*197];
  __shared__ float s_w2[64][17];
  for (int idx=t; idx<12544; idx+=256){
    int ipx = idx >> 6, c = idx & 63;
    s_mid[c*197 + ipx] = bf2f(mid[((size_t)b*196+ipx)*CC + g*64 + c]);
  }
  for (int idx=t; idx<64*16; idx+=256)
    s_w2[idx>>4][idx&15] = ldin(w2, (g*SPC + (idx>>4))*16 + (idx&15), isbf);
  __syncthreads();
  float b2v = ldin(b2, g, isbf);
  for (int p=t; p<HW28; p+=256) {
    int oy=p/28, ox=p-oy*28;
    float a = b2v;
    for (int c=0;c<64;c++) {
      #pragma unroll
      for (int kyi=0;kyi<2;kyi++){
        int ky=((oy+1)&1)+2*kyi; int ny=oy+1-ky;
        if (ny>=0){
          int iy=ny>>1;
          if (iy<14){
            #pragma unroll
            for (int kxi=0;kxi<2;kxi++){
              int kx=((ox+1)&1)+2*kxi; int nx=ox+1-kx;
              if (nx>=0){
                int ix=nx>>1;
                if (ix<14) a += s_mid[c*197+iy*14+ix]*s_w2[c][ky*4+kx];
              }
            }
          }
        }
      }
    }
    size_t oidx = out_elem_off + ((size_t)b*NGR+g)*HW28 + p;
    if (isbf) ((__hip_bfloat16*)outp)[oidx] = f2bf(a);
    else      ((float*)outp)[oidx] = a;
  }
}

extern "C" void kernel_launch(void* const* d_in, const int* in_sizes, int n_in,
                              void* d_out, int out_size, void* d_ws, size_t ws_size,
                              hipStream_t stream) {
  const void* x        = d_in[0];
  const void* convs_w0 = d_in[1];
  const void* convs_b0 = d_in[2];
  const void* convs_w  = d_in[3];
  const void* convs_b  = d_in[4];
  const void* gn_gamma = d_in[5];
  const void* gn_beta  = d_in[6];
  const void* fo_dw_w  = d_in[7];
  const void* fo_dw_b  = d_in[8];
  const void* fo_pw_w  = d_in[9];
  const void* fo_pw_b  = d_in[10];
  const void* so_dw_w  = d_in[11];
  const void* so_dw_b  = d_in[12];
  const void* so_pw_w  = d_in[13];
  const void* so_pw_b  = d_in[14];
  const void* up1_w    = d_in[15];
  const void* up1_b    = d_in[16];
  const void* sbn_g    = d_in[17];
  const void* sbn_b    = d_in[18];
  const void* up2_w    = d_in[19];
  const void* up2_b    = d_in[20];
  (void)in_sizes; (void)n_in; (void)out_size; (void)ws_size;

  // ws layout (bytes from wsb): act0 0 | wbuf 6,422,528 | actA 12,394,496 |
  // actB 17,113,088 | h_nchw 21,831,680 | bufF 25,444,352 | secN 29,057,024 |
  // wpack 33,775,616 | end 34,955,264.  mid (14,450,688) overlays act0+wbuf+actA
  // (all dead by head time; h = actB is untouched).
  int* flag = (int*)d_ws;
  char* wsb = (char*)d_ws + 16;
  __hip_bfloat16* act0   = (__hip_bfloat16*)(wsb);
  __hip_bfloat16* wbuf   = (__hip_bfloat16*)(wsb + 6422528);
  __hip_bfloat16* actA   = (__hip_bfloat16*)(wsb + 12394496);
  __hip_bfloat16* actB   = (__hip_bfloat16*)(wsb + 17113088);
  __hip_bfloat16* h_nchw = (__hip_bfloat16*)(wsb + 21831680);
  __hip_bfloat16* bufF   = (__hip_bfloat16*)(wsb + 25444352);
  __hip_bfloat16* secN   = (__hip_bfloat16*)(wsb + 29057024);
  __hip_bfloat16* wpack  = (__hip_bfloat16*)(wsb + 33775616);
  __hip_bfloat16* mid    = (__hip_bfloat16*)(wsb);

  detect_kernel<<<1, 1, 0, stream>>>((const unsigned short*)x, flag);

  xcvt_kernel<<<dim3(BB,8,7), 256, 0, stream>>>(x, flag, act0);
  wcvt0_kernel<<<CC, 256, 0, stream>>>(convs_w0, flag, wbuf);
  conv_mfma_kernel<256,8,14,14,196,2><<<dim3(64,9), 256, 0, stream>>>(
      act0, wbuf, convs_b0, 0, flag, actA);
  gn_nhwc_kernel<<<dim3(BB,36), 256, 0, stream>>>(actA, gn_gamma, gn_beta, 0, flag);

  __hip_bfloat16* cur = actA; __hip_bfloat16* nxt = actB;
  for (int i=0;i<7;i++){
    wcvtL_kernel<<<CC, 256, 0, stream>>>(convs_w, i, flag, wbuf);
    conv_mfma_kernel<576,18,7,7,64,1><<<dim3(64,9), 256, 0, stream>>>(
        cur, wbuf, convs_b, i*CC, flag, nxt);
    gn_nhwc_kernel<<<dim3(BB,36), 256, 0, stream>>>(nxt, gn_gamma, gn_beta, (i+1)*CC, flag);
    __hip_bfloat16* tmp=cur; cur=nxt; nxt=tmp;
  }
  // cur == actB (h, NHWC)

  nhwc2nchw_kernel<<<dim3(BB,18), 256, 0, stream>>>(cur, h_nchw);
  wpack_dc1_kernel<<<144, 256, 0, stream>>>(up1_w, flag, wpack);

  edge_msg_kernel<<<dim3(BB,NGR), 256, 0, stream>>>(h_nchw, h_nchw, fo_dw_w, fo_dw_b, fo_pw_w, fo_pw_b, flag, 0, bufF);
  edge_msg_kernel<<<dim3(BB,NGR), 256, 0, stream>>>(bufF, h_nchw, so_dw_w, so_dw_b, so_pw_w, so_pw_b, flag, 1, secN);

  // head 1 (input h = cur, NHWC)
  dc1_mfma_kernel<<<dim3(196,NGR), 256, 0, stream>>>(cur, wpack, up1_b, flag, mid);
  gn9_nhwc_kernel<<<dim3(BB,NGR), 256, 0, stream>>>(mid, sbn_g, sbn_b, flag);
  dc2_nhwc_kernel<<<dim3(BB,NGR), 256, 0, stream>>>(mid, up2_w, up2_b, flag, d_out, 0);
  // head 2 (input secN, NHWC)
  dc1_mfma_kernel<<<dim3(196,NGR), 256, 0, stream>>>(secN, wpack, up1_b, flag, mid);
  gn9_nhwc_kernel<<<dim3(BB,NGR), 256, 0, stream>>>(mid, sbn_g, sbn_b, flag);
  dc2_nhwc_kernel<<<dim3(BB,NGR), 256, 0, stream>>>(mid, up2_w, up2_b, flag, d_out, (size_t)BB*NGR*HW28);
}

// Round 6
// 1698.692 us; speedup vs baseline: 5.3201x; 1.1251x over previous
//
#include <hip/hip_runtime.h>
#include <hip/hip_bf16.h>

#define BB 64
#define CIN 256
#define CC 576
#define NGR 9
#define SPC 64
#define HW7 49
#define HW14 196
#define HW28 784

__device__ __constant__ int EDGE_SRC_C[24] = {1,3, 0,2,4, 1,5, 0,4,6, 1,3,5,7, 2,4,8, 3,7, 4,6,8, 5,7};
__device__ __constant__ int EDGE_OFF_C[9]  = {0,2,5,7,10,14,17,19,22};
__device__ __constant__ int EDGE_CNT_C[9]  = {2,3,2,3,4,3,2,3,2};

static __device__ __forceinline__ float bf2f(__hip_bfloat16 v){ return __bfloat162float(v); }
static __device__ __forceinline__ __hip_bfloat16 f2bf(float v){ return __float2bfloat16(v); }
static __device__ __forceinline__ float ldin(const void* p, size_t i, int isbf){
  return isbf ? bf2f(((const __hip_bfloat16*)p)[i]) : ((const float*)p)[i];
}

using bfrag = __attribute__((ext_vector_type(8))) short;
using f32x4 = __attribute__((ext_vector_type(4))) float;

// ---- dtype detector ------------------------------------------------------
__global__ void detect_kernel(const unsigned short* xs, int* flag) {
  if (threadIdx.x==0 && blockIdx.x==0) {
    int plaus = 0;
    for (int i=0;i<64;i++){
      unsigned short u = xs[2*i];
      int e = (u>>7)&0xFF;
      if (e>=100 && e<=140) plaus++;
    }
    *flag = (plaus >= 40) ? 1 : 0;
  }
}

// ---- x: [64,256,14,14] ext -> act0 NHWC bf16 [64][196][256] --------------
__global__ __launch_bounds__(256) void xcvt_kernel(
    const void* __restrict__ x, const int* __restrict__ flagp,
    __hip_bfloat16* __restrict__ act0) {
  const int b = blockIdx.x, icb = blockIdx.y, pxb = blockIdx.z, t = threadIdx.x;
  const int isbf = *flagp;
  __shared__ float lds[32][29];
  for (int idx=t; idx<32*28; idx+=256){
    int i = idx/28, j = idx - i*28;
    lds[i][j] = ldin(x, ((size_t)b*CIN + icb*32+i)*HW14 + pxb*28 + j, isbf);
  }
  __syncthreads();
  for (int idx=t; idx<28*32; idx+=256){
    int j = idx >> 5, i = idx & 31;
    act0[((size_t)b*HW14 + pxb*28 + j)*CIN + icb*32 + i] = f2bf(lds[i][j]);
  }
}

// ---- conv0 weights [576][256][9] ext -> [9][8][576][32] bf16 -------------
__global__ __launch_bounds__(256) void wcvt0_kernel(
    const void* __restrict__ w, const int* __restrict__ flagp,
    __hip_bfloat16* __restrict__ dst) {
  const int oc = blockIdx.x, t = threadIdx.x;
  const int isbf = *flagp;
  __shared__ float lds[2304];
  for (int idx=t; idx<2304; idx+=256)
    lds[idx] = ldin(w, (size_t)oc*2304 + idx, isbf);
  __syncthreads();
  for (int idx=t; idx<2304; idx+=256){
    int koff = idx >> 8, rem = idx & 255;
    int icb = rem >> 5, ici = rem & 31;
    dst[(((size_t)koff*8 + icb)*CC + oc)*32 + ici] = f2bf(lds[rem*9 + koff]);
  }
}

// ---- convs_w layer li [576][576][9] ext -> [9][18][576][32] bf16 ---------
__global__ __launch_bounds__(256) void wcvtL_kernel(
    const void* __restrict__ w, int li, const int* __restrict__ flagp,
    __hip_bfloat16* __restrict__ dst) {
  const int oc = blockIdx.x, t = threadIdx.x;
  const int isbf = *flagp;
  __shared__ float lds[5184];
  for (int idx=t; idx<5184; idx+=256)
    lds[idx] = ldin(w, ((size_t)li*CC + oc)*5184 + idx, isbf);
  __syncthreads();
  for (int idx=t; idx<5184; idx+=256){
    int koff = idx / 576, rem = idx - koff*576;
    int icb = rem >> 5, ici = rem & 31;
    dst[(((size_t)koff*18 + icb)*CC + oc)*32 + ici] = f2bf(lds[rem*9 + koff]);
  }
}

// ---- shared epilogue: +bias, GN over 4 complete groups (16ch x 49px),
//      ReLU, bf16x8 store to NHWC [b*64+px][576] -------------------------
static __device__ __forceinline__ void epilogue_gn(
    float* s_out, float* s_stats, const f32x4 (&acc)[2][2],
    int wm, int wn, int ln, int quad, int t,
    const void* bias, int bias_off,
    const void* gamma, const void* beta, int goff,
    int nbb, int isbf, int b,
    __hip_bfloat16* __restrict__ out)
{
  __syncthreads();   // any LDS aliased with s_out is fully read
  #pragma unroll
  for (int nf=0; nf<2; nf++){
    int chl = wn*32 + nf*16 + ln;
    float bv = ldin(bias, (size_t)bias_off + nbb + chl, isbf);
    #pragma unroll
    for (int mf=0; mf<2; mf++){
      #pragma unroll
      for (int r=0; r<4; r++){
        int px = wm*32 + mf*16 + quad*4 + r;
        s_out[chl*65 + px] = acc[mf][nf][r] + bv;
      }
    }
  }
  __syncthreads();
  {
    int wv = t >> 6, l = t & 63;
    float s=0.f, ss=0.f;
    for (int j=l; j<784; j+=64){
      int cq = j/49, px = j - cq*49;
      float v = s_out[(wv*16+cq)*65 + px];
      s += v; ss += v*v;
    }
    #pragma unroll
    for (int o=32;o>0;o>>=1){ s+=__shfl_down(s,o); ss+=__shfl_down(ss,o); }
    if (l==0){
      float mean=s/784.f, var=ss/784.f-mean*mean;
      s_stats[wv*2]=mean; s_stats[wv*2+1]=rsqrtf(fmaxf(var,0.f)+1e-5f);
    }
  }
  __syncthreads();
  for (int idx=t; idx<392; idx+=256){
    int px = idx>>3, ck = idx&7;
    alignas(16) __hip_bfloat16 tmp[8];
    #pragma unroll
    for (int u=0;u<8;u++){
      int chl = ck*8+u;
      int gi = chl>>4;
      float ga = ldin(gamma, (size_t)goff + nbb + chl, isbf);
      float be = ldin(beta,  (size_t)goff + nbb + chl, isbf);
      float v = (s_out[chl*65+px]-s_stats[gi*2])*s_stats[gi*2+1]*ga + be;
      tmp[u] = f2bf(fmaxf(v,0.f));
    }
    *(bfrag*)(out + ((size_t)b*64+px)*CC + nbb + ck*8) = *(const bfrag*)tmp;
  }
}

// ---- conv3x3 s1 p1 + GN + ReLU, LDS-staged A, MFMA -----------------------
// block (b, nchunk): A-image of batch b staged once (49 rows + zero row).
__global__ __launch_bounds__(256) void conv3_fused_kernel(
    const __hip_bfloat16* __restrict__ A,     // NHWC [64][64][576], px<49 valid
    const __hip_bfloat16* __restrict__ Wb,    // [9][18][576][32]
    const void* __restrict__ bias, int bias_off,
    const void* __restrict__ gamma, const void* __restrict__ beta, int goff,
    const int* __restrict__ flagp,
    __hip_bfloat16* __restrict__ out) {
  const int t = threadIdx.x;
  const int l = t & 63, w = t >> 6;
  const int wm = w & 1, wn = w >> 1;
  const int ln = l & 15, quad = l >> 4;
  const int b = blockIdx.x, nbb = blockIdx.y*64;

  __shared__ alignas(16) char smem[58400];      // 50 rows x 584 elems bf16
  __shared__ float s_stats[8];
  __hip_bfloat16* sA = (__hip_bfloat16*)smem;
  float* s_out = (float*)smem;                  // overlay after K-loop

  for (int idx=t*8; idx<28224; idx+=2048){
    int px = idx/576, ic = idx - px*576;
    *(bfrag*)(sA + px*584 + ic) = *(const bfrag*)(A + ((size_t)b*64+px)*CC + ic);
  }
  if (t < 72){
    bfrag z = {0,0,0,0,0,0,0,0};
    *(bfrag*)(sA + 49*584 + t*8) = z;
  }
  __syncthreads();

  int yy[2], xx[2]; bool pv[2];
  #pragma unroll
  for (int mf=0; mf<2; mf++){
    int p = wm*32 + mf*16 + ln;
    pv[mf] = p<49; yy[mf]=p/7; xx[mf]=p-yy[mf]*7;
  }

  f32x4 acc[2][2];
  #pragma unroll
  for (int i=0;i<2;i++)
    #pragma unroll
    for (int j=0;j<2;j++) acc[i][j] = (f32x4){0.f,0.f,0.f,0.f};

  for (int koff=0; koff<9; koff++){
    const int dy = koff/3 - 1, dx = koff - (koff/3)*3 - 1;
    int sy0=yy[0]+dy, sx0=xx[0]+dx;
    int r0 = (pv[0]&&sy0>=0&&sy0<7&&sx0>=0&&sx0<7) ? sy0*7+sx0 : 49;
    int sy1=yy[1]+dy, sx1=xx[1]+dx;
    int r1 = (pv[1]&&sy1>=0&&sy1<7&&sx1>=0&&sx1<7) ? sy1*7+sx1 : 49;
    const __hip_bfloat16* a0p = sA + r0*584 + quad*8;
    const __hip_bfloat16* a1p = sA + r1*584 + quad*8;
    const __hip_bfloat16* wp0 = Wb + ((size_t)koff*18*576 + nbb + wn*32 + ln)*32 + quad*8;
    for (int icb=0; icb<18; icb++){
      bfrag a0 = *(const bfrag*)(a0p + icb*32);
      bfrag a1 = *(const bfrag*)(a1p + icb*32);
      const __hip_bfloat16* wp = wp0 + (size_t)icb*(576*32);
      bfrag b0 = *(const bfrag*)(wp);
      bfrag b1 = *(const bfrag*)(wp + 16*32);
      acc[0][0] = __builtin_amdgcn_mfma_f32_16x16x32_bf16(a0, b0, acc[0][0], 0,0,0);
      acc[1][0] = __builtin_amdgcn_mfma_f32_16x16x32_bf16(a1, b0, acc[1][0], 0,0,0);
      acc[0][1] = __builtin_amdgcn_mfma_f32_16x16x32_bf16(a0, b1, acc[0][1], 0,0,0);
      acc[1][1] = __builtin_amdgcn_mfma_f32_16x16x32_bf16(a1, b1, acc[1][1], 0,0,0);
    }
  }

  epilogue_gn(s_out, s_stats, acc, wm, wn, ln, quad, t,
              bias, bias_off, gamma, beta, goff, nbb, *flagp, b, out);
}

// ---- conv0 3x3 s2 p1 + GN + ReLU, chunked LDS A, MFMA --------------------
__global__ __launch_bounds__(256) void conv0_fused_kernel(
    const __hip_bfloat16* __restrict__ A,     // NHWC [64][196][256]
    const __hip_bfloat16* __restrict__ Wb,    // [9][8][576][32]
    const void* __restrict__ bias,
    const void* __restrict__ gamma, const void* __restrict__ beta,
    const int* __restrict__ flagp,
    __hip_bfloat16* __restrict__ out) {       // NHWC [64][64][576]
  const int t = threadIdx.x;
  const int l = t & 63, w = t >> 6;
  const int wm = w & 1, wn = w >> 1;
  const int ln = l & 15, quad = l >> 4;
  const int b = blockIdx.x, nbb = blockIdx.y*64;

  __shared__ alignas(16) __hip_bfloat16 sC[197*40];  // 196 rows + zero row, +8 pad
  __shared__ alignas(16) float s_out_arr[64*65];
  __shared__ float s_stats[8];

  if (t < 4){
    bfrag z = {0,0,0,0,0,0,0,0};
    *(bfrag*)(sC + 196*40 + t*8) = z;
  }

  int yy[2], xx[2]; bool pv[2];
  #pragma unroll
  for (int mf=0; mf<2; mf++){
    int p = wm*32 + mf*16 + ln;
    pv[mf] = p<49; yy[mf]=p/7; xx[mf]=p-yy[mf]*7;
  }

  f32x4 acc[2][2];
  #pragma unroll
  for (int i=0;i<2;i++)
    #pragma unroll
    for (int j=0;j<2;j++) acc[i][j] = (f32x4){0.f,0.f,0.f,0.f};

  for (int icb=0; icb<8; icb++){
    __syncthreads();
    for (int idx=t*8; idx<6272; idx+=2048){
      int px = idx>>5, ic = idx&31;
      *(bfrag*)(sC + px*40 + ic) = *(const bfrag*)(A + ((size_t)b*196+px)*256 + icb*32 + ic);
    }
    __syncthreads();
    for (int koff=0; koff<9; koff++){
      const int dy = koff/3 - 1, dx = koff - (koff/3)*3 - 1;
      int sy0=2*yy[0]+dy, sx0=2*xx[0]+dx;
      int r0 = (pv[0]&&sy0>=0&&sy0<14&&sx0>=0&&sx0<14) ? sy0*14+sx0 : 196;
      int sy1=2*yy[1]+dy, sx1=2*xx[1]+dx;
      int r1 = (pv[1]&&sy1>=0&&sy1<14&&sx1>=0&&sx1<14) ? sy1*14+sx1 : 196;
      bfrag a0 = *(const bfrag*)(sC + r0*40 + quad*8);
      bfrag a1 = *(const bfrag*)(sC + r1*40 + quad*8);
      const __hip_bfloat16* wp = Wb + ((size_t)(koff*8+icb)*576 + nbb + wn*32 + ln)*32 + quad*8;
      bfrag b0 = *(const bfrag*)(wp);
      bfrag b1 = *(const bfrag*)(wp + 16*32);
      acc[0][0] = __builtin_amdgcn_mfma_f32_16x16x32_bf16(a0, b0, acc[0][0], 0,0,0);
      acc[1][0] = __builtin_amdgcn_mfma_f32_16x16x32_bf16(a1, b0, acc[1][0], 0,0,0);
      acc[0][1] = __builtin_amdgcn_mfma_f32_16x16x32_bf16(a0, b1, acc[0][1], 0,0,0);
      acc[1][1] = __builtin_amdgcn_mfma_f32_16x16x32_bf16(a1, b1, acc[1][1], 0,0,0);
    }
  }

  epilogue_gn(s_out_arr, s_stats, acc, wm, wn, ln, quad, t,
              bias, 0, gamma, beta, 0, nbb, *flagp, b, out);
}

// ---- NHWC [64][64][576] -> NCHW [64][576][49] bf16 ----------------------
__global__ __launch_bounds__(256) void nhwc2nchw_kernel(
    const __hip_bfloat16* __restrict__ src,
    __hip_bfloat16* __restrict__ dst) {
  const int b = blockIdx.x, cb = blockIdx.y, t = threadIdx.x;
  __shared__ float lds[49][33];
  for (int idx=t; idx<49*32; idx+=256){
    int p = idx >> 5, i = idx & 31;
    lds[p][i] = bf2f(src[((size_t)b*64+p)*CC + cb*32 + i]);
  }
  __syncthreads();
  for (int idx=t; idx<32*49; idx+=256){
    int c = idx/49, p = idx - c*49;
    dst[((size_t)b*CC + cb*32 + c)*HW7 + p] = f2bf(lds[p][c]);
  }
}

// ---- edge message passing (NCHW in); out NCHW or NHWC --------------------
__global__ __launch_bounds__(256) void edge_msg_kernel(
    const __hip_bfloat16* __restrict__ src_feat,
    const __hip_bfloat16* __restrict__ base,
    const void* __restrict__ dw_w,
    const void* __restrict__ dw_b,
    const void* __restrict__ pw_w,
    const void* __restrict__ pw_b,
    const int* __restrict__ flagp, int out_nhwc,
    __hip_bfloat16* __restrict__ out) {
  const int isbf = *flagp;
  const int b = blockIdx.x, dst = blockIdx.y, t = threadIdx.x;
  const int lc = t >> 2;
  const int q = t & 3;
  const int p0 = q*12 + (q?1:0);
  const int cnt = q? 12:13;

  __shared__ float s_pin[64][132];
  __shared__ float s_y[64][52];
  __shared__ __hip_bfloat16 s_pw[64][66];
  __shared__ float s_dw[64][26];

  float acc[13];
  #pragma unroll
  for (int i=0;i<13;i++) acc[i]=0.f;

  const int eoff = EDGE_OFF_C[dst];
  const int ecnt = EDGE_CNT_C[dst];
  for (int k=0;k<ecnt;k++) {
    const int e = eoff + k;
    const int src = EDGE_SRC_C[e];
    __syncthreads();
    const __hip_bfloat16* sp = src_feat + ((size_t)b*CC + src*SPC)*HW7;
    for (int idx=t; idx<64*132; idx+=256) {
      int c = idx/132, rem = idx%132, r = rem/12, col = rem%12;
      int iy=r-2, ix=col-2;
      float v=0.f;
      if (iy>=0&&iy<7&&ix>=0&&ix<7) v = bf2f(sp[c*HW7 + iy*7 + ix]);
      s_pin[c][rem]=v;
    }
    for (int idx=t; idx<64*25; idx+=256)
      s_dw[idx/25][idx%25] = ldin(dw_w, (size_t)e*1600 + idx, isbf);
    for (int idx=t; idx<64*64; idx+=256)
      s_pw[idx>>6][idx&63] = f2bf(ldin(pw_w, (size_t)e*4096 + idx, isbf));
    __syncthreads();
    {
      float dwb = ldin(dw_b, e*64 + lc, isbf);
      float wd[25];
      #pragma unroll
      for (int j=0;j<25;j++) wd[j]=s_dw[lc][j];
      for (int pi=0; pi<cnt; pi++) {
        int p = p0 + pi; int oy=p/7, ox=p-oy*7;
        float a = dwb;
        #pragma unroll
        for (int u=0;u<5;u++)
          #pragma unroll
          for (int vv=0;vv<5;vv++)
            a += s_pin[lc][(oy+u)*12 + ox+vv] * wd[u*5+vv];
        s_y[lc][p] = a;
      }
    }
    __syncthreads();
    {
      float pb = ldin(pw_b, e*64 + lc, isbf);
      for (int c=0;c<64;c++){
        float wv = bf2f(s_pw[lc][c]);
        #pragma unroll
        for (int pi=0;pi<13;pi++)
          if (pi<cnt) acc[pi] += s_y[c][p0+pi]*wv;
      }
      #pragma unroll
      for (int pi=0;pi<13;pi++) if (pi<cnt) acc[pi]+=pb;
    }
  }
  const size_t o0 = ((size_t)b*CC + dst*SPC + lc)*HW7;
  for (int pi=0;pi<cnt;pi++){
    int p=p0+pi;
    float val = bf2f(base[o0+p]) + acc[pi];
    if (out_nhwc) out[((size_t)b*64 + p)*CC + dst*SPC + lc] = f2bf(val);
    else          out[o0+p] = f2bf(val);
  }
}

// ---- up1_w [576][64][16] ext -> wpack [9][16tap][64oc][64ic] bf16 --------
__global__ __launch_bounds__(256) void wpack_dc1_kernel(
    const void* __restrict__ w1, const int* __restrict__ flagp,
    __hip_bfloat16* __restrict__ dst) {
  const int gtap = blockIdx.x, t = threadIdx.x;
  const int isbf = *flagp;
  const int g = gtap >> 4, tap = gtap & 15;
  for (int idx=t; idx<64*64; idx+=256){
    int oc = idx >> 6, ic = idx & 63;
    dst[((size_t)gtap*64 + oc)*64 + ic] =
        f2bf(ldin(w1, ((size_t)(g*64+ic)*64 + oc)*16 + tap, isbf));
  }
}

// ---- deconv1 via MFMA: H NHWC -> mid NHWC [64][196][576] -----------------
__global__ __launch_bounds__(256) void dc1_mfma_kernel(
    const __hip_bfloat16* __restrict__ H,
    const __hip_bfloat16* __restrict__ Wp,   // [g*16+tap][oc][ic]
    const void* __restrict__ b1,
    const int* __restrict__ flagp,
    __hip_bfloat16* __restrict__ mid) {
  const int tid = threadIdx.x;
  const int l = tid & 63;
  const int w = tid >> 6;
  const int wm = w & 1, wn = w >> 1;
  const int g = blockIdx.y;
  const int mt = blockIdx.x*64 + wm*32;
  const int nb = wn*32;
  const int ln = l & 15;
  const int quad = l >> 4;

  int bb[2], iy_t[2][4], ix_t[2][4]; bool vy[2][4], vx[2][4];
  #pragma unroll
  for (int mf=0; mf<2; mf++){
    int m = mt + mf*16 + ln;
    int b = m/196, px = m - b*196;
    bb[mf] = b;
    int oy = px/14, ox = px - oy*14;
    #pragma unroll
    for (int k=0;k<4;k++){
      int ny = oy+1-k; vy[mf][k] = (ny>=0) && !(ny&1) && (ny>>1)<7; iy_t[mf][k]=(ny>>1)*7;
      int nx = ox+1-k; vx[mf][k] = (nx>=0) && !(nx&1) && (nx>>1)<7; ix_t[mf][k]=nx>>1;
    }
  }

  f32x4 acc[2][2];
  #pragma unroll
  for (int i=0;i<2;i++)
    #pragma unroll
    for (int j=0;j<2;j++) acc[i][j] = (f32x4){0.f,0.f,0.f,0.f};
  const bfrag zf = {0,0,0,0,0,0,0,0};

  for (int tap=0; tap<16; tap++){
    const int ky = tap>>2, kx = tap&3;
    int ipx[2]; bool tv[2];
    #pragma unroll
    for (int mf=0; mf<2; mf++){
      tv[mf] = vy[mf][ky] && vx[mf][kx];
      ipx[mf] = iy_t[mf][ky] + ix_t[mf][kx];
    }
    const __hip_bfloat16* wrow = Wp + (((size_t)(g*16+tap)*64 + nb + ln)*64);
    #pragma unroll
    for (int half=0; half<2; half++){
      const int icq = half*32 + quad*8;
      bfrag a0 = tv[0] ? *(const bfrag*)(H + ((size_t)(bb[0]*64 + ipx[0]))*CC + g*64 + icq) : zf;
      bfrag a1 = tv[1] ? *(const bfrag*)(H + ((size_t)(bb[1]*64 + ipx[1]))*CC + g*64 + icq) : zf;
      bfrag b0 = *(const bfrag*)(wrow + icq);
      bfrag b1v = *(const bfrag*)(wrow + 16*64 + icq);
      acc[0][0] = __builtin_amdgcn_mfma_f32_16x16x32_bf16(a0, b0,  acc[0][0], 0,0,0);
      acc[1][0] = __builtin_amdgcn_mfma_f32_16x16x32_bf16(a1, b0,  acc[1][0], 0,0,0);
      acc[0][1] = __builtin_amdgcn_mfma_f32_16x16x32_bf16(a0, b1v, acc[0][1], 0,0,0);
      acc[1][1] = __builtin_amdgcn_mfma_f32_16x16x32_bf16(a1, b1v, acc[1][1], 0,0,0);
    }
  }

  const int isbf = *flagp;
  #pragma unroll
  for (int nf=0; nf<2; nf++){
    int n = g*64 + nb + nf*16 + ln;
    float bv = ldin(b1, n, isbf);
    #pragma unroll
    for (int mf=0; mf<2; mf++){
      #pragma unroll
      for (int r=0; r<4; r++){
        int m = mt + mf*16 + quad*4 + r;
        int b = m/196, px = m - b*196;
        mid[((size_t)b*196 + px)*CC + n] = f2bf(acc[mf][nf][r] + bv);
      }
    }
  }
}

// ---- GN(9 groups: 64ch x 196px) + ReLU on mid NHWC, in place -------------
__global__ __launch_bounds__(256) void gn9_nhwc_kernel(
    __hip_bfloat16* __restrict__ mid,
    const void* __restrict__ gamma, const void* __restrict__ beta,
    const int* __restrict__ flagp) {
  const int b = blockIdx.x, g = blockIdx.y, t = threadIdx.x;
  const int ci = t & 63;
  float s=0.f, ss=0.f;
  for (int i=t; i<12544; i+=256){
    int px = i >> 6;
    float v = bf2f(mid[((size_t)b*196+px)*CC + g*64 + ci]);
    s += v; ss += v*v;
  }
  #pragma unroll
  for (int o=32;o>0;o>>=1){ s+=__shfl_down(s,o); ss+=__shfl_down(ss,o); }
  __shared__ float red[8]; __shared__ float stats[2];
  int wid = t>>6;
  if ((t&63)==0){ red[wid]=s; red[4+wid]=ss; }
  __syncthreads();
  if (t==0){
    float S=red[0]+red[1]+red[2]+red[3];
    float SS=red[4]+red[5]+red[6]+red[7];
    float mean=S/12544.f, var=SS/12544.f-mean*mean;
    stats[0]=mean; stats[1]=rsqrtf(fmaxf(var,0.f)+1e-5f);
  }
  __syncthreads();
  const int isbf = *flagp;
  float mean=stats[0], inv=stats[1];
  float ga=ldin(gamma, g*64+ci, isbf), be=ldin(beta, g*64+ci, isbf);
  for (int i=t; i<12544; i+=256){
    int px = i >> 6;
    size_t idx = ((size_t)b*196+px)*CC + g*64 + ci;
    float v = (bf2f(mid[idx])-mean)*inv*ga + be;
    mid[idx] = f2bf(fmaxf(v, 0.f));
  }
}

// ---- deconv2 from mid NHWC: [64ic x 196px] -> 1ch 28x28 per (b,g) --------
__global__ __launch_bounds__(256) void dc2_nhwc_kernel(
    const __hip_bfloat16* __restrict__ mid,
    const void* __restrict__ w2,
    const void* __restrict__ b2,
    const int* __restrict__ flagp,
    void* __restrict__ outp,
    size_t out_elem_off) {
  const int isbf = *flagp;
  const int b=blockIdx.x, g=blockIdx.y, t=threadIdx.x;
  __shared__ float s_mid[64*197];
  __shared__ float s_w2[64][17];
  for (int idx=t; idx<12544; idx+=256){
    int ipx = idx >> 6, c = idx & 63;
    s_mid[c*197 + ipx] = bf2f(mid[((size_t)b*196+ipx)*CC + g*64 + c]);
  }
  for (int idx=t; idx<64*16; idx+=256)
    s_w2[idx>>4][idx&15] = ldin(w2, (g*SPC + (idx>>4))*16 + (idx&15), isbf);
  __syncthreads();
  float b2v = ldin(b2, g, isbf);
  for (int p=t; p<HW28; p+=256) {
    int oy=p/28, ox=p-oy*28;
    float a = b2v;
    for (int c=0;c<64;c++) {
      #pragma unroll
      for (int kyi=0;kyi<2;kyi++){
        int ky=((oy+1)&1)+2*kyi; int ny=oy+1-ky;
        if (ny>=0){
          int iy=ny>>1;
          if (iy<14){
            #pragma unroll
            for (int kxi=0;kxi<2;kxi++){
              int kx=((ox+1)&1)+2*kxi; int nx=ox+1-kx;
              if (nx>=0){
                int ix=nx>>1;
                if (ix<14) a += s_mid[c*197+iy*14+ix]*s_w2[c][ky*4+kx];
              }
            }
          }
        }
      }
    }
    size_t oidx = out_elem_off + ((size_t)b*NGR+g)*HW28 + p;
    if (isbf) ((__hip_bfloat16*)outp)[oidx] = f2bf(a);
    else      ((float*)outp)[oidx] = a;
  }
}

extern "C" void kernel_launch(void* const* d_in, const int* in_sizes, int n_in,
                              void* d_out, int out_size, void* d_ws, size_t ws_size,
                              hipStream_t stream) {
  const void* x        = d_in[0];
  const void* convs_w0 = d_in[1];
  const void* convs_b0 = d_in[2];
  const void* convs_w  = d_in[3];
  const void* convs_b  = d_in[4];
  const void* gn_gamma = d_in[5];
  const void* gn_beta  = d_in[6];
  const void* fo_dw_w  = d_in[7];
  const void* fo_dw_b  = d_in[8];
  const void* fo_pw_w  = d_in[9];
  const void* fo_pw_b  = d_in[10];
  const void* so_dw_w  = d_in[11];
  const void* so_dw_b  = d_in[12];
  const void* so_pw_w  = d_in[13];
  const void* so_pw_b  = d_in[14];
  const void* up1_w    = d_in[15];
  const void* up1_b    = d_in[16];
  const void* sbn_g    = d_in[17];
  const void* sbn_b    = d_in[18];
  const void* up2_w    = d_in[19];
  const void* up2_b    = d_in[20];
  (void)in_sizes; (void)n_in; (void)out_size; (void)ws_size;

  // ws layout (bytes from wsb): act0 0 | wbuf 6,422,528 | actA 12,394,496 |
  // actB 17,113,088 | h_nchw 21,831,680 | bufF 25,444,352 | secN 29,057,024 |
  // wpack 33,775,616 | end 34,955,264.  mid (14,450,688) overlays act0..actA.
  int* flag = (int*)d_ws;
  char* wsb = (char*)d_ws + 16;
  __hip_bfloat16* act0   = (__hip_bfloat16*)(wsb);
  __hip_bfloat16* wbuf   = (__hip_bfloat16*)(wsb + 6422528);
  __hip_bfloat16* actA   = (__hip_bfloat16*)(wsb + 12394496);
  __hip_bfloat16* actB   = (__hip_bfloat16*)(wsb + 17113088);
  __hip_bfloat16* h_nchw = (__hip_bfloat16*)(wsb + 21831680);
  __hip_bfloat16* bufF   = (__hip_bfloat16*)(wsb + 25444352);
  __hip_bfloat16* secN   = (__hip_bfloat16*)(wsb + 29057024);
  __hip_bfloat16* wpack  = (__hip_bfloat16*)(wsb + 33775616);
  __hip_bfloat16* mid    = (__hip_bfloat16*)(wsb);

  detect_kernel<<<1, 1, 0, stream>>>((const unsigned short*)x, flag);

  xcvt_kernel<<<dim3(BB,8,7), 256, 0, stream>>>(x, flag, act0);
  wcvt0_kernel<<<CC, 256, 0, stream>>>(convs_w0, flag, wbuf);
  conv0_fused_kernel<<<dim3(64,9), 256, 0, stream>>>(
      act0, wbuf, convs_b0, gn_gamma, gn_beta, flag, actA);

  __hip_bfloat16* cur = actA; __hip_bfloat16* nxt = actB;
  for (int i=0;i<7;i++){
    wcvtL_kernel<<<CC, 256, 0, stream>>>(convs_w, i, flag, wbuf);
    conv3_fused_kernel<<<dim3(64,9), 256, 0, stream>>>(
        cur, wbuf, convs_b, i*CC, gn_gamma, gn_beta, (i+1)*CC, flag, nxt);
    __hip_bfloat16* tmp=cur; cur=nxt; nxt=tmp;
  }
  // cur == actB (h, NHWC)

  nhwc2nchw_kernel<<<dim3(BB,18), 256, 0, stream>>>(cur, h_nchw);
  wpack_dc1_kernel<<<144, 256, 0, stream>>>(up1_w, flag, wpack);

  edge_msg_kernel<<<dim3(BB,NGR), 256, 0, stream>>>(h_nchw, h_nchw, fo_dw_w, fo_dw_b, fo_pw_w, fo_pw_b, flag, 0, bufF);
  edge_msg_kernel<<<dim3(BB,NGR), 256, 0, stream>>>(bufF, h_nchw, so_dw_w, so_dw_b, so_pw_w, so_pw_b, flag, 1, secN);

  // head 1 (input h = cur, NHWC)
  dc1_mfma_kernel<<<dim3(196,NGR), 256, 0, stream>>>(cur, wpack, up1_b, flag, mid);
  gn9_nhwc_kernel<<<dim3(BB,NGR), 256, 0, stream>>>(mid, sbn_g, sbn_b, flag);
  dc2_nhwc_kernel<<<dim3(BB,NGR), 256, 0, stream>>>(mid, up2_w, up2_b, flag, d_out, 0);
  // head 2 (input secN, NHWC)
  dc1_mfma_kernel<<<dim3(196,NGR), 256, 0, stream>>>(secN, wpack, up1_b, flag, mid);
  gn9_nhwc_kernel<<<dim3(BB,NGR), 256, 0, stream>>>(mid, sbn_g, sbn_b, flag);
  dc2_nhwc_kernel<<<dim3(BB,NGR), 256, 0, stream>>>(mid, up2_w, up2_b, flag, d_out, (size_t)BB*NGR*HW28);
}

// Round 8
// 1291.256 us; speedup vs baseline: 6.9988x; 1.3155x over previous
//
#include <hip/hip_runtime.h>
#include <hip/hip_bf16.h>

#define BB 64
#define CIN 256
#define CC 576
#define NGR 9
#define SPC 64
#define HW7 49
#define HW14 196
#define HW28 784

__device__ __constant__ int EDGE_SRC_C[24] = {1,3, 0,2,4, 1,5, 0,4,6, 1,3,5,7, 2,4,8, 3,7, 4,6,8, 5,7};
__device__ __constant__ int EDGE_OFF_C[9]  = {0,2,5,7,10,14,17,19,22};
__device__ __constant__ int EDGE_CNT_C[9]  = {2,3,2,3,4,3,2,3,2};

static __device__ __forceinline__ float bf2f(__hip_bfloat16 v){ return __bfloat162float(v); }
static __device__ __forceinline__ __hip_bfloat16 f2bf(float v){ return __float2bfloat16(v); }
static __device__ __forceinline__ float ldin(const void* p, size_t i, int isbf){
  return isbf ? bf2f(((const __hip_bfloat16*)p)[i]) : ((const float*)p)[i];
}

using bfrag = __attribute__((ext_vector_type(8))) short;
using f32x4 = __attribute__((ext_vector_type(4))) float;

// ---- dtype detector ------------------------------------------------------
__global__ void detect_kernel(const unsigned short* xs, int* flag) {
  if (threadIdx.x==0 && blockIdx.x==0) {
    int plaus = 0;
    for (int i=0;i<64;i++){
      unsigned short u = xs[2*i];
      int e = (u>>7)&0xFF;
      if (e>=100 && e<=140) plaus++;
    }
    *flag = (plaus >= 40) ? 1 : 0;
  }
}

// ---- x: [64,256,14,14] ext -> act0 NHWC bf16 [64][196][256] --------------
__global__ __launch_bounds__(256) void xcvt_kernel(
    const void* __restrict__ x, const int* __restrict__ flagp,
    __hip_bfloat16* __restrict__ act0) {
  const int b = blockIdx.x, icb = blockIdx.y, pxb = blockIdx.z, t = threadIdx.x;
  const int isbf = *flagp;
  __shared__ float lds[32][29];
  for (int idx=t; idx<32*28; idx+=256){
    int i = idx/28, j = idx - i*28;
    lds[i][j] = ldin(x, ((size_t)b*CIN + icb*32+i)*HW14 + pxb*28 + j, isbf);
  }
  __syncthreads();
  for (int idx=t; idx<28*32; idx+=256){
    int j = idx >> 5, i = idx & 31;
    act0[((size_t)b*HW14 + pxb*28 + j)*CIN + icb*32 + i] = f2bf(lds[i][j]);
  }
}

// ---- conv0 weights [576][256][9] ext -> [9][8][576][32] bf16 -------------
__global__ __launch_bounds__(256) void wcvt0_kernel(
    const void* __restrict__ w, const int* __restrict__ flagp,
    __hip_bfloat16* __restrict__ dst) {
  const int oc = blockIdx.x, t = threadIdx.x;
  const int isbf = *flagp;
  __shared__ float lds[2304];
  for (int idx=t; idx<2304; idx+=256)
    lds[idx] = ldin(w, (size_t)oc*2304 + idx, isbf);
  __syncthreads();
  for (int idx=t; idx<2304; idx+=256){
    int koff = idx >> 8, rem = idx & 255;
    int icb = rem >> 5, ici = rem & 31;
    dst[(((size_t)koff*8 + icb)*CC + oc)*32 + ici] = f2bf(lds[rem*9 + koff]);
  }
}

// ---- convs_w layer li [576][576][9] ext -> [9][18][576][32] bf16 ---------
__global__ __launch_bounds__(256) void wcvtL_kernel(
    const void* __restrict__ w, int li, const int* __restrict__ flagp,
    __hip_bfloat16* __restrict__ dst) {
  const int oc = blockIdx.x, t = threadIdx.x;
  const int isbf = *flagp;
  __shared__ float lds[5184];
  for (int idx=t; idx<5184; idx+=256)
    lds[idx] = ldin(w, ((size_t)li*CC + oc)*5184 + idx, isbf);
  __syncthreads();
  for (int idx=t; idx<5184; idx+=256){
    int koff = idx / 576, rem = idx - koff*576;
    int icb = rem >> 5, ici = rem & 31;
    dst[(((size_t)koff*18 + icb)*CC + oc)*32 + ici] = f2bf(lds[rem*9 + koff]);
  }
}

// ---- shared epilogue: +bias, GN over 4 complete groups (16ch x 49px),
//      ReLU, bf16x8 store to NHWC [b*64+px][576] -------------------------
static __device__ __forceinline__ void epilogue_gn(
    float* s_out, float* s_stats, const f32x4 (&acc)[2][2],
    int wm, int wn, int ln, int quad, int t,
    const void* bias, int bias_off,
    const void* gamma, const void* beta, int goff,
    int nbb, int isbf, int b,
    __hip_bfloat16* __restrict__ out)
{
  __syncthreads();   // any LDS aliased with s_out is fully read
  #pragma unroll
  for (int nf=0; nf<2; nf++){
    int chl = wn*32 + nf*16 + ln;
    float bv = ldin(bias, (size_t)bias_off + nbb + chl, isbf);
    #pragma unroll
    for (int mf=0; mf<2; mf++){
      #pragma unroll
      for (int r=0; r<4; r++){
        int px = wm*32 + mf*16 + quad*4 + r;
        s_out[chl*65 + px] = acc[mf][nf][r] + bv;
      }
    }
  }
  __syncthreads();
  {
    int wv = t >> 6, l = t & 63;
    float s=0.f, ss=0.f;
    for (int j=l; j<784; j+=64){
      int cq = j/49, px = j - cq*49;
      float v = s_out[(wv*16+cq)*65 + px];
      s += v; ss += v*v;
    }
    #pragma unroll
    for (int o=32;o>0;o>>=1){ s+=__shfl_down(s,o); ss+=__shfl_down(ss,o); }
    if (l==0){
      float mean=s/784.f, var=ss/784.f-mean*mean;
      s_stats[wv*2]=mean; s_stats[wv*2+1]=rsqrtf(fmaxf(var,0.f)+1e-5f);
    }
  }
  __syncthreads();
  for (int idx=t; idx<392; idx+=256){
    int px = idx>>3, ck = idx&7;
    alignas(16) __hip_bfloat16 tmp[8];
    #pragma unroll
    for (int u=0;u<8;u++){
      int chl = ck*8+u;
      int gi = chl>>4;
      float ga = ldin(gamma, (size_t)goff + nbb + chl, isbf);
      float be = ldin(beta,  (size_t)goff + nbb + chl, isbf);
      float v = (s_out[chl*65+px]-s_stats[gi*2])*s_stats[gi*2+1]*ga + be;
      tmp[u] = f2bf(fmaxf(v,0.f));
    }
    *(bfrag*)(out + ((size_t)b*64+px)*CC + nbb + ck*8) = *(const bfrag*)tmp;
  }
}

// ---- conv3x3 s1 p1 + GN + ReLU; ic-chunked double-buffered LDS (16.6 KB) -
__global__ __launch_bounds__(256) void conv3_v2_kernel(
    const __hip_bfloat16* __restrict__ A,     // NHWC [64][64][576], px<49 valid
    const __hip_bfloat16* __restrict__ Wb,    // [9][18][576][32]
    const void* __restrict__ bias, int bias_off,
    const void* __restrict__ gamma, const void* __restrict__ beta, int goff,
    const int* __restrict__ flagp,
    __hip_bfloat16* __restrict__ out) {
  const int t = threadIdx.x;
  const int l = t & 63, w = t >> 6;
  const int wm = w & 1, wn = w >> 1;
  const int ln = l & 15, quad = l >> 4;
  const int b = blockIdx.x, nbb = blockIdx.y*64;

  __shared__ alignas(16) char smem[16640];      // s_out 64x65 f32 overlays sA0/sA1
  __shared__ float s_stats[8];
  __hip_bfloat16* sA0 = (__hip_bfloat16*)smem;          // 50 rows x 40 = 4000 B
  __hip_bfloat16* sA1 = (__hip_bfloat16*)(smem + 4000);
  float* s_out = (float*)smem;

  if (t < 8){
    bfrag z = {0,0,0,0,0,0,0,0};
    __hip_bfloat16* sb = (t<4)? sA0 : sA1;
    *(bfrag*)(sb + 49*40 + (t&3)*8) = z;
  }

  int r0a[9], r1a[9];
  {
    int p0 = wm*32 + ln, p1 = p0+16;
    int y0=p0/7, x0=p0-y0*7, y1=p1/7, x1=p1-y1*7;
    bool v0=p0<49, v1=p1<49;
    #pragma unroll
    for (int koff=0;koff<9;koff++){
      int dy=koff/3-1, dx=koff-(koff/3)*3-1;
      int sy0=y0+dy,sx0=x0+dx, sy1=y1+dy,sx1=x1+dx;
      r0a[koff] = (v0&&sy0>=0&&sy0<7&&sx0>=0&&sx0<7)? sy0*7+sx0 : 49;
      r1a[koff] = (v1&&sy1>=0&&sy1<7&&sx1>=0&&sx1<7)? sy1*7+sx1 : 49;
    }
  }

  f32x4 acc[2][2];
  #pragma unroll
  for (int i=0;i<2;i++)
    #pragma unroll
    for (int j=0;j<2;j++) acc[i][j] = (f32x4){0.f,0.f,0.f,0.f};

  const int px_s = t>>2, ic_s = (t&3)*8;     // staging coords, t<196 active
  const __hip_bfloat16* Abase = A + ((size_t)b*64 + px_s)*CC + ic_s;

  if (t<196) *(bfrag*)(sA0 + px_s*40 + ic_s) = *(const bfrag*)(Abase);
  __syncthreads();

  const int nidx = nbb + wn*32 + ln;
  for (int icb=0; icb<18; icb++){
    __hip_bfloat16* curb = (icb&1)? sA1 : sA0;
    if (icb<17 && t<196){
      __hip_bfloat16* nxtb = (icb&1)? sA0 : sA1;
      *(bfrag*)(nxtb + px_s*40 + ic_s) = *(const bfrag*)(Abase + (icb+1)*32);
    }
    const __hip_bfloat16* wpB = Wb + (size_t)icb*18432 + nidx*32 + quad*8;
    #pragma unroll
    for (int koff=0;koff<9;koff++){
      bfrag a0 = *(const bfrag*)(curb + r0a[koff]*40 + quad*8);
      bfrag a1 = *(const bfrag*)(curb + r1a[koff]*40 + quad*8);
      const __hip_bfloat16* wp = wpB + (size_t)koff*331776;
      bfrag b0 = *(const bfrag*)(wp);
      bfrag b1 = *(const bfrag*)(wp + 512);
      acc[0][0] = __builtin_amdgcn_mfma_f32_16x16x32_bf16(a0, b0, acc[0][0], 0,0,0);
      acc[1][0] = __builtin_amdgcn_mfma_f32_16x16x32_bf16(a1, b0, acc[1][0], 0,0,0);
      acc[0][1] = __builtin_amdgcn_mfma_f32_16x16x32_bf16(a0, b1, acc[0][1], 0,0,0);
      acc[1][1] = __builtin_amdgcn_mfma_f32_16x16x32_bf16(a1, b1, acc[1][1], 0,0,0);
    }
    __syncthreads();
  }

  epilogue_gn(s_out, s_stats, acc, wm, wn, ln, quad, t,
              bias, bias_off, gamma, beta, goff, nbb, *flagp, b, out);
}

// ---- conv0 3x3 s2 p1 + GN + ReLU, chunked LDS A, MFMA (validated) --------
__global__ __launch_bounds__(256) void conv0_fused_kernel(
    const __hip_bfloat16* __restrict__ A,     // NHWC [64][196][256]
    const __hip_bfloat16* __restrict__ Wb,    // [9][8][576][32]
    const void* __restrict__ bias,
    const void* __restrict__ gamma, const void* __restrict__ beta,
    const int* __restrict__ flagp,
    __hip_bfloat16* __restrict__ out) {       // NHWC [64][64][576]
  const int t = threadIdx.x;
  const int l = t & 63, w = t >> 6;
  const int wm = w & 1, wn = w >> 1;
  const int ln = l & 15, quad = l >> 4;
  const int b = blockIdx.x, nbb = blockIdx.y*64;

  __shared__ alignas(16) __hip_bfloat16 sC[197*40];
  __shared__ alignas(16) float s_out_arr[64*65];
  __shared__ float s_stats[8];

  if (t < 4){
    bfrag z = {0,0,0,0,0,0,0,0};
    *(bfrag*)(sC + 196*40 + t*8) = z;
  }

  int yy[2], xx[2]; bool pv[2];
  #pragma unroll
  for (int mf=0; mf<2; mf++){
    int p = wm*32 + mf*16 + ln;
    pv[mf] = p<49; yy[mf]=p/7; xx[mf]=p-yy[mf]*7;
  }

  f32x4 acc[2][2];
  #pragma unroll
  for (int i=0;i<2;i++)
    #pragma unroll
    for (int j=0;j<2;j++) acc[i][j] = (f32x4){0.f,0.f,0.f,0.f};

  for (int icb=0; icb<8; icb++){
    __syncthreads();
    for (int idx=t*8; idx<6272; idx+=2048){
      int px = idx>>5, ic = idx&31;
      *(bfrag*)(sC + px*40 + ic) = *(const bfrag*)(A + ((size_t)b*196+px)*256 + icb*32 + ic);
    }
    __syncthreads();
    for (int koff=0; koff<9; koff++){
      const int dy = koff/3 - 1, dx = koff - (koff/3)*3 - 1;
      int sy0=2*yy[0]+dy, sx0=2*xx[0]+dx;
      int r0 = (pv[0]&&sy0>=0&&sy0<14&&sx0>=0&&sx0<14) ? sy0*14+sx0 : 196;
      int sy1=2*yy[1]+dy, sx1=2*xx[1]+dx;
      int r1 = (pv[1]&&sy1>=0&&sy1<14&&sx1>=0&&sx1<14) ? sy1*14+sx1 : 196;
      bfrag a0 = *(const bfrag*)(sC + r0*40 + quad*8);
      bfrag a1 = *(const bfrag*)(sC + r1*40 + quad*8);
      const __hip_bfloat16* wp = Wb + ((size_t)(koff*8+icb)*576 + nbb + wn*32 + ln)*32 + quad*8;
      bfrag b0 = *(const bfrag*)(wp);
      bfrag b1 = *(const bfrag*)(wp + 16*32);
      acc[0][0] = __builtin_amdgcn_mfma_f32_16x16x32_bf16(a0, b0, acc[0][0], 0,0,0);
      acc[1][0] = __builtin_amdgcn_mfma_f32_16x16x32_bf16(a1, b0, acc[1][0], 0,0,0);
      acc[0][1] = __builtin_amdgcn_mfma_f32_16x16x32_bf16(a0, b1, acc[0][1], 0,0,0);
      acc[1][1] = __builtin_amdgcn_mfma_f32_16x16x32_bf16(a1, b1, acc[1][1], 0,0,0);
    }
  }

  epilogue_gn(s_out_arr, s_stats, acc, wm, wn, ln, quad, t,
              bias, 0, gamma, beta, 0, nbb, *flagp, b, out);
}

// ---- depthwise 5x5 per edge: F NHWC -> Y[e][(b*49+px)][64] bf16 ----------
// FIX (R7 bug): staging must be a grid-stride loop — block has 256 threads,
// previous `if (t<392)` left rows 32..48 + zero-row unstaged.
__global__ __launch_bounds__(256) void dw_edge_kernel(
    const __hip_bfloat16* __restrict__ F,
    const void* __restrict__ dw_w,   // [24][64][25]
    const void* __restrict__ dw_b,   // [24][64]
    const int* __restrict__ flagp,
    __hip_bfloat16* __restrict__ Y) {
  const int b = blockIdx.x, e = blockIdx.y, t = threadIdx.x;
  const int isbf = *flagp;
  const int src = EDGE_SRC_C[e];
  __shared__ alignas(16) __hip_bfloat16 sA[50*72];   // 49 px rows + zero row
  for (int idx=t; idx<400; idx+=256){
    if (idx < 392){
      int px = idx>>3, ic = (idx&7)*8;
      *(bfrag*)(sA + px*72 + ic) = *(const bfrag*)(F + ((size_t)b*64+px)*CC + src*64 + ic);
    } else {
      bfrag z = {0,0,0,0,0,0,0,0};
      *(bfrag*)(sA + 49*72 + (idx-392)*8) = z;
    }
  }
  __syncthreads();
  const int ch = t & 63, wv = t >> 6;
  float wd[25];
  #pragma unroll
  for (int j=0;j<25;j++) wd[j] = ldin(dw_w, (size_t)e*1600 + ch*25 + j, isbf);
  float dwb = ldin(dw_b, e*64 + ch, isbf);
  for (int px=wv; px<49; px+=4){
    int oy=px/7, ox=px-oy*7;
    float a = dwb;
    #pragma unroll
    for (int u=0;u<5;u++){
      int py = oy+u-2;
      bool vy = (py>=0)&&(py<7);
      #pragma unroll
      for (int v=0;v<5;v++){
        int pxx = ox+v-2;
        int r = (vy && pxx>=0 && pxx<7) ? py*7+pxx : 49;
        a += bf2f(sA[r*72 + ch]) * wd[u*5+v];
      }
    }
    Y[((size_t)(e*64+b)*49 + px)*64 + ch] = f2bf(a);
  }
}

// ---- pack pointwise weights to bf16 [24][64oc][64ic] ---------------------
__global__ __launch_bounds__(256) void pwpack_kernel(
    const void* __restrict__ pw_fo, const void* __restrict__ pw_so,
    const int* __restrict__ flagp,
    __hip_bfloat16* __restrict__ dfo, __hip_bfloat16* __restrict__ dso) {
  const int e = blockIdx.x, t = threadIdx.x;
  const int isbf = *flagp;
  for (int idx=t; idx<4096; idx+=256){
    dfo[(size_t)e*4096+idx] = f2bf(ldin(pw_fo, (size_t)e*4096+idx, isbf));
    dso[(size_t)e*4096+idx] = f2bf(ldin(pw_so, (size_t)e*4096+idx, isbf));
  }
}

// ---- pointwise + segment-sum via MFMA: out = base + sum_e Y_e @ pw_e^T ---
__global__ __launch_bounds__(256) void pw_seg_kernel(
    const __hip_bfloat16* __restrict__ Y,     // [24][3136][64]
    const __hip_bfloat16* __restrict__ base,  // NHWC [64][64][576]
    const __hip_bfloat16* __restrict__ pwb,   // [24][64oc][64ic] bf16
    const void* __restrict__ pw_b,            // [24][64] ext
    const int* __restrict__ flagp,
    __hip_bfloat16* __restrict__ out) {       // NHWC
  const int t = threadIdx.x, l = t & 63, w = t >> 6;
  const int wm = w & 1, wn = w >> 1;
  const int ln = l & 15, quad = l >> 4;
  const int dst = blockIdx.y;
  const int mt = blockIdx.x*64 + wm*32;
  const int m0 = mt + ln, m1 = m0 + 16;

  f32x4 acc[2][2];
  #pragma unroll
  for (int i=0;i<2;i++)
    #pragma unroll
    for (int j=0;j<2;j++) acc[i][j] = (f32x4){0.f,0.f,0.f,0.f};

  const int eoff = EDGE_OFF_C[dst], ecnt = EDGE_CNT_C[dst];
  for (int k=0;k<ecnt;k++){
    const __hip_bfloat16* Ye = Y + (size_t)(eoff+k)*3136*64;
    const __hip_bfloat16* pe = pwb + (size_t)(eoff+k)*4096;
    #pragma unroll
    for (int ks=0; ks<2; ks++){
      const int kq = ks*32 + quad*8;
      bfrag a0 = *(const bfrag*)(Ye + (size_t)m0*64 + kq);
      bfrag a1 = *(const bfrag*)(Ye + (size_t)m1*64 + kq);
      bfrag b0 = *(const bfrag*)(pe + (wn*32+ln)*64 + kq);
      bfrag b1 = *(const bfrag*)(pe + (wn*32+ln+16)*64 + kq);
      acc[0][0] = __builtin_amdgcn_mfma_f32_16x16x32_bf16(a0, b0, acc[0][0], 0,0,0);
      acc[1][0] = __builtin_amdgcn_mfma_f32_16x16x32_bf16(a1, b0, acc[1][0], 0,0,0);
      acc[0][1] = __builtin_amdgcn_mfma_f32_16x16x32_bf16(a0, b1, acc[0][1], 0,0,0);
      acc[1][1] = __builtin_amdgcn_mfma_f32_16x16x32_bf16(a1, b1, acc[1][1], 0,0,0);
    }
  }

  const int isbf = *flagp;
  #pragma unroll
  for (int nf=0; nf<2; nf++){
    int n = wn*32 + nf*16 + ln;
    float pbs = 0.f;
    for (int k=0;k<ecnt;k++) pbs += ldin(pw_b, (size_t)(eoff+k)*64 + n, isbf);
    #pragma unroll
    for (int mf=0; mf<2; mf++){
      #pragma unroll
      for (int r=0; r<4; r++){
        int m = mt + mf*16 + quad*4 + r;
        int bb = m/49, px = m - bb*49;
        size_t oi = ((size_t)bb*64 + px)*CC + dst*64 + n;
        out[oi] = f2bf(bf2f(base[oi]) + acc[mf][nf][r] + pbs);
      }
    }
  }
}

// ---- up1_w [576][64][16] ext -> wpack [9][16tap][64oc][64ic] bf16 --------
__global__ __launch_bounds__(256) void wpack_dc1_kernel(
    const void* __restrict__ w1, const int* __restrict__ flagp,
    __hip_bfloat16* __restrict__ dst) {
  const int gtap = blockIdx.x, t = threadIdx.x;
  const int isbf = *flagp;
  const int g = gtap >> 4, tap = gtap & 15;
  for (int idx=t; idx<64*64; idx+=256){
    int oc = idx >> 6, ic = idx & 63;
    dst[((size_t)gtap*64 + oc)*64 + ic] =
        f2bf(ldin(w1, ((size_t)(g*64+ic)*64 + oc)*16 + tap, isbf));
  }
}

// ---- deconv1 via MFMA: H NHWC -> mid NHWC [64][196][576] -----------------
__global__ __launch_bounds__(256) void dc1_mfma_kernel(
    const __hip_bfloat16* __restrict__ H,
    const __hip_bfloat16* __restrict__ Wp,   // [g*16+tap][oc][ic]
    const void* __restrict__ b1,
    const int* __restrict__ flagp,
    __hip_bfloat16* __restrict__ mid) {
  const int tid = threadIdx.x;
  const int l = tid & 63;
  const int w = tid >> 6;
  const int wm = w & 1, wn = w >> 1;
  const int g = blockIdx.y;
  const int mt = blockIdx.x*64 + wm*32;
  const int nb = wn*32;
  const int ln = l & 15;
  const int quad = l >> 4;

  int bb[2], iy_t[2][4], ix_t[2][4]; bool vy[2][4], vx[2][4];
  #pragma unroll
  for (int mf=0; mf<2; mf++){
    int m = mt + mf*16 + ln;
    int b = m/196, px = m - b*196;
    bb[mf] = b;
    int oy = px/14, ox = px - oy*14;
    #pragma unroll
    for (int k=0;k<4;k++){
      int ny = oy+1-k; vy[mf][k] = (ny>=0) && !(ny&1) && (ny>>1)<7; iy_t[mf][k]=(ny>>1)*7;
      int nx = ox+1-k; vx[mf][k] = (nx>=0) && !(nx&1) && (nx>>1)<7; ix_t[mf][k]=nx>>1;
    }
  }

  f32x4 acc[2][2];
  #pragma unroll
  for (int i=0;i<2;i++)
    #pragma unroll
    for (int j=0;j<2;j++) acc[i][j] = (f32x4){0.f,0.f,0.f,0.f};
  const bfrag zf = {0,0,0,0,0,0,0,0};

  for (int tap=0; tap<16; tap++){
    const int ky = tap>>2, kx = tap&3;
    int ipx[2]; bool tv[2];
    #pragma unroll
    for (int mf=0; mf<2; mf++){
      tv[mf] = vy[mf][ky] && vx[mf][kx];
      ipx[mf] = iy_t[mf][ky] + ix_t[mf][kx];
    }
    const __hip_bfloat16* wrow = Wp + (((size_t)(g*16+tap)*64 + nb + ln)*64);
    #pragma unroll
    for (int half=0; half<2; half++){
      const int icq = half*32 + quad*8;
      bfrag a0 = tv[0] ? *(const bfrag*)(H + ((size_t)(bb[0]*64 + ipx[0]))*CC + g*64 + icq) : zf;
      bfrag a1 = tv[1] ? *(const bfrag*)(H + ((size_t)(bb[1]*64 + ipx[1]))*CC + g*64 + icq) : zf;
      bfrag b0 = *(const bfrag*)(wrow + icq);
      bfrag b1v = *(const bfrag*)(wrow + 16*64 + icq);
      acc[0][0] = __builtin_amdgcn_mfma_f32_16x16x32_bf16(a0, b0,  acc[0][0], 0,0,0);
      acc[1][0] = __builtin_amdgcn_mfma_f32_16x16x32_bf16(a1, b0,  acc[1][0], 0,0,0);
      acc[0][1] = __builtin_amdgcn_mfma_f32_16x16x32_bf16(a0, b1v, acc[0][1], 0,0,0);
      acc[1][1] = __builtin_amdgcn_mfma_f32_16x16x32_bf16(a1, b1v, acc[1][1], 0,0,0);
    }
  }

  const int isbf = *flagp;
  #pragma unroll
  for (int nf=0; nf<2; nf++){
    int n = g*64 + nb + nf*16 + ln;
    float bv = ldin(b1, n, isbf);
    #pragma unroll
    for (int mf=0; mf<2; mf++){
      #pragma unroll
      for (int r=0; r<4; r++){
        int m = mt + mf*16 + quad*4 + r;
        int b = m/196, px = m - b*196;
        mid[((size_t)b*196 + px)*CC + n] = f2bf(acc[mf][nf][r] + bv);
      }
    }
  }
}

// ---- GN(9 groups: 64ch x 196px) + ReLU on mid NHWC, in place -------------
__global__ __launch_bounds__(256) void gn9_nhwc_kernel(
    __hip_bfloat16* __restrict__ mid,
    const void* __restrict__ gamma, const void* __restrict__ beta,
    const int* __restrict__ flagp) {
  const int b = blockIdx.x, g = blockIdx.y, t = threadIdx.x;
  const int ci = t & 63;
  float s=0.f, ss=0.f;
  for (int i=t; i<12544; i+=256){
    int px = i >> 6;
    float v = bf2f(mid[((size_t)b*196+px)*CC + g*64 + ci]);
    s += v; ss += v*v;
  }
  #pragma unroll
  for (int o=32;o>0;o>>=1){ s+=__shfl_down(s,o); ss+=__shfl_down(ss,o); }
  __shared__ float red[8]; __shared__ float stats[2];
  int wid = t>>6;
  if ((t&63)==0){ red[wid]=s; red[4+wid]=ss; }
  __syncthreads();
  if (t==0){
    float S=red[0]+red[1]+red[2]+red[3];
    float SS=red[4]+red[5]+red[6]+red[7];
    float mean=S/12544.f, var=SS/12544.f-mean*mean;
    stats[0]=mean; stats[1]=rsqrtf(fmaxf(var,0.f)+1e-5f);
  }
  __syncthreads();
  const int isbf = *flagp;
  float mean=stats[0], inv=stats[1];
  float ga=ldin(gamma, g*64+ci, isbf), be=ldin(beta, g*64+ci, isbf);
  for (int i=t; i<12544; i+=256){
    int px = i >> 6;
    size_t idx = ((size_t)b*196+px)*CC + g*64 + ci;
    float v = (bf2f(mid[idx])-mean)*inv*ga + be;
    mid[idx] = f2bf(fmaxf(v, 0.f));
  }
}

// ---- deconv2 from mid NHWC: [64ic x 196px] -> 1ch 28x28 per (b,g) --------
__global__ __launch_bounds__(256) void dc2_nhwc_kernel(
    const __hip_bfloat16* __restrict__ mid,
    const void* __restrict__ w2,
    const void* __restrict__ b2,
    const int* __restrict__ flagp,
    void* __restrict__ outp,
    size_t out_elem_off) {
  const int isbf = *flagp;
  const int b=blockIdx.x, g=blockIdx.y, t=threadIdx.x;
  __shared__ float s_mid[64*197];
  __shared__ float s_w2[64][17];
  for (int idx=t; idx<12544; idx+=256){
    int ipx = idx >> 6, c = idx & 63;
    s_mid[c*197 + ipx] = bf2f(mid[((size_t)b*196+ipx)*CC + g*64 + c]);
  }
  for (int idx=t; idx<64*16; idx+=256)
    s_w2[idx>>4][idx&15] = ldin(w2, (g*SPC + (idx>>4))*16 + (idx&15), isbf);
  __syncthreads();
  float b2v = ldin(b2, g, isbf);
  for (int p=t; p<HW28; p+=256) {
    int oy=p/28, ox=p-oy*28;
    float a = b2v;
    for (int c=0;c<64;c++) {
      #pragma unroll
      for (int kyi=0;kyi<2;kyi++){
        int ky=((oy+1)&1)+2*kyi; int ny=oy+1-ky;
        if (ny>=0){
          int iy=ny>>1;
          if (iy<14){
            #pragma unroll
            for (int kxi=0;kxi<2;kxi++){
              int kx=((ox+1)&1)+2*kxi; int nx=ox+1-kx;
              if (nx>=0){
                int ix=nx>>1;
                if (ix<14) a += s_mid[c*197+iy*14+ix]*s_w2[c][ky*4+kx];
              }
            }
          }
        }
      }
    }
    size_t oidx = out_elem_off + ((size_t)b*NGR+g)*HW28 + p;
    if (isbf) ((__hip_bfloat16*)outp)[oidx] = f2bf(a);
    else      ((float*)outp)[oidx] = a;
  }
}

extern "C" void kernel_launch(void* const* d_in, const int* in_sizes, int n_in,
                              void* d_out, int out_size, void* d_ws, size_t ws_size,
                              hipStream_t stream) {
  const void* x        = d_in[0];
  const void* convs_w0 = d_in[1];
  const void* convs_b0 = d_in[2];
  const void* convs_w  = d_in[3];
  const void* convs_b  = d_in[4];
  const void* gn_gamma = d_in[5];
  const void* gn_beta  = d_in[6];
  const void* fo_dw_w  = d_in[7];
  const void* fo_dw_b  = d_in[8];
  const void* fo_pw_w  = d_in[9];
  const void* fo_pw_b  = d_in[10];
  const void* so_dw_w  = d_in[11];
  const void* so_dw_b  = d_in[12];
  const void* so_pw_w  = d_in[13];
  const void* so_pw_b  = d_in[14];
  const void* up1_w    = d_in[15];
  const void* up1_b    = d_in[16];
  const void* sbn_g    = d_in[17];
  const void* sbn_b    = d_in[18];
  const void* up2_w    = d_in[19];
  const void* up2_b    = d_in[20];
  (void)in_sizes; (void)n_in; (void)out_size; (void)ws_size;

  int* flag = (int*)d_ws;
  char* wsb = (char*)d_ws + 16;
  __hip_bfloat16* act0   = (__hip_bfloat16*)(wsb);
  __hip_bfloat16* wbuf   = (__hip_bfloat16*)(wsb + 6422528);
  __hip_bfloat16* actA   = (__hip_bfloat16*)(wsb + 12394496);
  __hip_bfloat16* actB   = (__hip_bfloat16*)(wsb + 17113088);
  __hip_bfloat16* bufF   = (__hip_bfloat16*)(wsb + 21831680);
  __hip_bfloat16* secN   = (__hip_bfloat16*)(wsb + 26550272);
  __hip_bfloat16* wpack  = (__hip_bfloat16*)(wsb + 31268864);
  __hip_bfloat16* pwbF   = (__hip_bfloat16*)(wsb + 32448512);
  __hip_bfloat16* pwbS   = (__hip_bfloat16*)(wsb + 32645120);
  __hip_bfloat16* Y      = (__hip_bfloat16*)(wsb);
  __hip_bfloat16* mid    = (__hip_bfloat16*)(wsb);

  detect_kernel<<<1, 1, 0, stream>>>((const unsigned short*)x, flag);

  xcvt_kernel<<<dim3(BB,8,7), 256, 0, stream>>>(x, flag, act0);
  wcvt0_kernel<<<CC, 256, 0, stream>>>(convs_w0, flag, wbuf);
  conv0_fused_kernel<<<dim3(64,9), 256, 0, stream>>>(
      act0, wbuf, convs_b0, gn_gamma, gn_beta, flag, actA);

  __hip_bfloat16* cur = actA; __hip_bfloat16* nxt = actB;
  for (int i=0;i<7;i++){
    wcvtL_kernel<<<CC, 256, 0, stream>>>(convs_w, i, flag, wbuf);
    conv3_v2_kernel<<<dim3(64,9), 256, 0, stream>>>(
        cur, wbuf, convs_b, i*CC, gn_gamma, gn_beta, (i+1)*CC, flag, nxt);
    __hip_bfloat16* tmp=cur; cur=nxt; nxt=tmp;
  }
  // cur == actB (h, NHWC)

  wpack_dc1_kernel<<<144, 256, 0, stream>>>(up1_w, flag, wpack);
  pwpack_kernel<<<24, 256, 0, stream>>>(fo_pw_w, so_pw_w, flag, pwbF, pwbS);

  // edge pass 1: first = h + seg(pw(dw(h)))
  dw_edge_kernel<<<dim3(BB,24), 256, 0, stream>>>(cur, fo_dw_w, fo_dw_b, flag, Y);
  pw_seg_kernel<<<dim3(49,NGR), 256, 0, stream>>>(Y, cur, pwbF, fo_pw_b, flag, bufF);
  // edge pass 2: second = h + seg(pw(dw(first)))
  dw_edge_kernel<<<dim3(BB,24), 256, 0, stream>>>(bufF, so_dw_w, so_dw_b, flag, Y);
  pw_seg_kernel<<<dim3(49,NGR), 256, 0, stream>>>(Y, cur, pwbS, so_pw_b, flag, secN);

  // head 1 (input h = cur, NHWC)
  dc1_mfma_kernel<<<dim3(196,NGR), 256, 0, stream>>>(cur, wpack, up1_b, flag, mid);
  gn9_nhwc_kernel<<<dim3(BB,NGR), 256, 0, stream>>>(mid, sbn_g, sbn_b, flag);
  dc2_nhwc_kernel<<<dim3(BB,NGR), 256, 0, stream>>>(mid, up2_w, up2_b, flag, d_out, 0);
  // head 2 (input secN, NHWC)
  dc1_mfma_kernel<<<dim3(196,NGR), 256, 0, stream>>>(secN, wpack, up1_b, flag, mid);
  gn9_nhwc_kernel<<<dim3(BB,NGR), 256, 0, stream>>>(mid, sbn_g, sbn_b, flag);
  dc2_nhwc_kernel<<<dim3(BB,NGR), 256, 0, stream>>>(mid, up2_w, up2_b, flag, d_out, (size_t)BB*NGR*HW28);
}

// Round 9
// 1073.112 us; speedup vs baseline: 8.4216x; 1.2033x over previous
//
#include <hip/hip_runtime.h>
#include <hip/hip_bf16.h>

#define BB 64
#define CIN 256
#define CC 576
#define NGR 9
#define SPC 64
#define HW7 49
#define HW14 196
#define HW28 784

__device__ __constant__ int EDGE_SRC_C[24] = {1,3, 0,2,4, 1,5, 0,4,6, 1,3,5,7, 2,4,8, 3,7, 4,6,8, 5,7};
__device__ __constant__ int EDGE_OFF_C[9]  = {0,2,5,7,10,14,17,19,22};
__device__ __constant__ int EDGE_CNT_C[9]  = {2,3,2,3,4,3,2,3,2};

static __device__ __forceinline__ float bf2f(__hip_bfloat16 v){ return __bfloat162float(v); }
static __device__ __forceinline__ __hip_bfloat16 f2bf(float v){ return __float2bfloat16(v); }
static __device__ __forceinline__ float ldin(const void* p, size_t i, int isbf){
  return isbf ? bf2f(((const __hip_bfloat16*)p)[i]) : ((const float*)p)[i];
}

using bfrag = __attribute__((ext_vector_type(8))) short;
using f32x4 = __attribute__((ext_vector_type(4))) float;

// ---- dtype detector ------------------------------------------------------
__global__ void detect_kernel(const unsigned short* xs, int* flag) {
  if (threadIdx.x==0 && blockIdx.x==0) {
    int plaus = 0;
    for (int i=0;i<64;i++){
      unsigned short u = xs[2*i];
      int e = (u>>7)&0xFF;
      if (e>=100 && e<=140) plaus++;
    }
    *flag = (plaus >= 40) ? 1 : 0;
  }
}

// ---- x: [64,256,14,14] ext -> act0 NHWC bf16 [64][196][256] --------------
__global__ __launch_bounds__(256) void xcvt_kernel(
    const void* __restrict__ x, const int* __restrict__ flagp,
    __hip_bfloat16* __restrict__ act0) {
  const int b = blockIdx.x, icb = blockIdx.y, pxb = blockIdx.z, t = threadIdx.x;
  const int isbf = *flagp;
  __shared__ float lds[32][29];
  for (int idx=t; idx<32*28; idx+=256){
    int i = idx/28, j = idx - i*28;
    lds[i][j] = ldin(x, ((size_t)b*CIN + icb*32+i)*HW14 + pxb*28 + j, isbf);
  }
  __syncthreads();
  for (int idx=t; idx<28*32; idx+=256){
    int j = idx >> 5, i = idx & 31;
    act0[((size_t)b*HW14 + pxb*28 + j)*CIN + icb*32 + i] = f2bf(lds[i][j]);
  }
}

// ---- conv0 weights [576][256][9] ext -> [9][8][576][32] bf16 -------------
__global__ __launch_bounds__(256) void wcvt0_kernel(
    const void* __restrict__ w, const int* __restrict__ flagp,
    __hip_bfloat16* __restrict__ dst) {
  const int oc = blockIdx.x, t = threadIdx.x;
  const int isbf = *flagp;
  __shared__ float lds[2304];
  for (int idx=t; idx<2304; idx+=256)
    lds[idx] = ldin(w, (size_t)oc*2304 + idx, isbf);
  __syncthreads();
  for (int idx=t; idx<2304; idx+=256){
    int koff = idx >> 8, rem = idx & 255;
    int icb = rem >> 5, ici = rem & 31;
    dst[(((size_t)koff*8 + icb)*CC + oc)*32 + ici] = f2bf(lds[rem*9 + koff]);
  }
}

// ---- convs_w layer li [576][576][9] ext -> [9][18][576][32] bf16 ---------
__global__ __launch_bounds__(256) void wcvtL_kernel(
    const void* __restrict__ w, int li, const int* __restrict__ flagp,
    __hip_bfloat16* __restrict__ dst) {
  const int oc = blockIdx.x, t = threadIdx.x;
  const int isbf = *flagp;
  __shared__ float lds[5184];
  for (int idx=t; idx<5184; idx+=256)
    lds[idx] = ldin(w, ((size_t)li*CC + oc)*5184 + idx, isbf);
  __syncthreads();
  for (int idx=t; idx<5184; idx+=256){
    int koff = idx / 576, rem = idx - koff*576;
    int icb = rem >> 5, ici = rem & 31;
    dst[(((size_t)koff*18 + icb)*CC + oc)*32 + ici] = f2bf(lds[rem*9 + koff]);
  }
}

// ---- epilogue for conv0 (64 ch / 4 GN groups, validated) -----------------
static __device__ __forceinline__ void epilogue_gn(
    float* s_out, float* s_stats, const f32x4 (&acc)[2][2],
    int wm, int wn, int ln, int quad, int t,
    const void* bias, int bias_off,
    const void* gamma, const void* beta, int goff,
    int nbb, int isbf, int b,
    __hip_bfloat16* __restrict__ out)
{
  __syncthreads();
  #pragma unroll
  for (int nf=0; nf<2; nf++){
    int chl = wn*32 + nf*16 + ln;
    float bv = ldin(bias, (size_t)bias_off + nbb + chl, isbf);
    #pragma unroll
    for (int mf=0; mf<2; mf++){
      #pragma unroll
      for (int r=0; r<4; r++){
        int px = wm*32 + mf*16 + quad*4 + r;
        s_out[chl*65 + px] = acc[mf][nf][r] + bv;
      }
    }
  }
  __syncthreads();
  {
    int wv = t >> 6, l = t & 63;
    float s=0.f, ss=0.f;
    for (int j=l; j<784; j+=64){
      int cq = j/49, px = j - cq*49;
      float v = s_out[(wv*16+cq)*65 + px];
      s += v; ss += v*v;
    }
    #pragma unroll
    for (int o=32;o>0;o>>=1){ s+=__shfl_down(s,o); ss+=__shfl_down(ss,o); }
    if (l==0){
      float mean=s/784.f, var=ss/784.f-mean*mean;
      s_stats[wv*2]=mean; s_stats[wv*2+1]=rsqrtf(fmaxf(var,0.f)+1e-5f);
    }
  }
  __syncthreads();
  for (int idx=t; idx<392; idx+=256){
    int px = idx>>3, ck = idx&7;
    alignas(16) __hip_bfloat16 tmp[8];
    #pragma unroll
    for (int u=0;u<8;u++){
      int chl = ck*8+u;
      int gi = chl>>4;
      float ga = ldin(gamma, (size_t)goff + nbb + chl, isbf);
      float be = ldin(beta,  (size_t)goff + nbb + chl, isbf);
      float v = (s_out[chl*65+px]-s_stats[gi*2])*s_stats[gi*2+1]*ga + be;
      tmp[u] = f2bf(fmaxf(v,0.f));
    }
    *(bfrag*)(out + ((size_t)b*64+px)*CC + nbb + ck*8) = *(const bfrag*)tmp;
  }
}

// ---- conv3x3 s1 p1 + GN + ReLU; N-split (grid 64x18), 32N/block ----------
// wave tile 32Mx16N; ic-chunked double-buffered LDS A (8 KB); high occupancy.
__global__ __launch_bounds__(256) void conv3_v3_kernel(
    const __hip_bfloat16* __restrict__ A,     // NHWC [64][64][576], px<49 valid
    const __hip_bfloat16* __restrict__ Wb,    // [9][18][576][32]
    const void* __restrict__ bias, int bias_off,
    const void* __restrict__ gamma, const void* __restrict__ beta, int goff,
    const int* __restrict__ flagp,
    __hip_bfloat16* __restrict__ out) {
  const int t = threadIdx.x;
  const int l = t & 63, w = t >> 6;
  const int wm = w & 1, wn = (w >> 1) & 1;
  const int ln = l & 15, quad = l >> 4;
  const int b = blockIdx.x, nbb = blockIdx.y*32;
  const int isbf = *flagp;

  __shared__ alignas(16) char smem[8320];   // sA0 4000 | sA1 4000; s_out 32x65 f32 overlays
  __shared__ float s_stats[4];
  __hip_bfloat16* sA0 = (__hip_bfloat16*)smem;
  __hip_bfloat16* sA1 = (__hip_bfloat16*)(smem + 4000);
  float* s_out = (float*)smem;

  if (t < 8){
    bfrag z = {0,0,0,0,0,0,0,0};
    __hip_bfloat16* sb = (t<4)? sA0 : sA1;
    *(bfrag*)(sb + 49*40 + (t&3)*8) = z;
  }

  int r0a[9], r1a[9];
  {
    int p0 = wm*32 + ln, p1 = p0+16;
    int y0=p0/7, x0=p0-y0*7, y1=p1/7, x1=p1-y1*7;
    bool v0=p0<49, v1=p1<49;
    #pragma unroll
    for (int koff=0;koff<9;koff++){
      int dy=koff/3-1, dx=koff-(koff/3)*3-1;
      int sy0=y0+dy,sx0=x0+dx, sy1=y1+dy,sx1=x1+dx;
      r0a[koff] = (v0&&sy0>=0&&sy0<7&&sx0>=0&&sx0<7)? sy0*7+sx0 : 49;
      r1a[koff] = (v1&&sy1>=0&&sy1<7&&sx1>=0&&sx1<7)? sy1*7+sx1 : 49;
    }
  }

  f32x4 acc2[2];
  acc2[0] = (f32x4){0.f,0.f,0.f,0.f};
  acc2[1] = (f32x4){0.f,0.f,0.f,0.f};

  const int px_s = t>>2, ic_s = (t&3)*8;     // staging coords, t<196 active
  const __hip_bfloat16* Abase = A + ((size_t)b*64 + px_s)*CC + ic_s;

  if (t<196) *(bfrag*)(sA0 + px_s*40 + ic_s) = *(const bfrag*)(Abase);
  __syncthreads();

  const int nidx = nbb + wn*16 + ln;
  for (int icb=0; icb<18; icb++){
    __hip_bfloat16* curb = (icb&1)? sA1 : sA0;
    if (icb<17 && t<196){
      __hip_bfloat16* nxtb = (icb&1)? sA0 : sA1;
      *(bfrag*)(nxtb + px_s*40 + ic_s) = *(const bfrag*)(Abase + (icb+1)*32);
    }
    const __hip_bfloat16* wpB = Wb + (size_t)icb*18432 + (size_t)nidx*32 + quad*8;
    #pragma unroll
    for (int koff=0;koff<9;koff++){
      bfrag a0 = *(const bfrag*)(curb + r0a[koff]*40 + quad*8);
      bfrag a1 = *(const bfrag*)(curb + r1a[koff]*40 + quad*8);
      bfrag b0 = *(const bfrag*)(wpB + (size_t)koff*331776);
      acc2[0] = __builtin_amdgcn_mfma_f32_16x16x32_bf16(a0, b0, acc2[0], 0,0,0);
      acc2[1] = __builtin_amdgcn_mfma_f32_16x16x32_bf16(a1, b0, acc2[1], 0,0,0);
    }
    __syncthreads();
  }

  // epilogue: 32 ch x 49 px, 2 GN groups of 16 ch
  {
    const int chl = wn*16 + ln;
    float bv = ldin(bias, (size_t)bias_off + nbb + chl, isbf);
    #pragma unroll
    for (int mf=0; mf<2; mf++)
      #pragma unroll
      for (int r=0;r<4;r++){
        int px = wm*32 + mf*16 + quad*4 + r;
        s_out[chl*65 + px] = acc2[mf][r] + bv;
      }
  }
  __syncthreads();
  {
    int wv = t >> 6, l2 = t & 63;
    if (wv < 2){
      float s=0.f, ss=0.f;
      for (int j=l2; j<784; j+=64){
        int cq = j/49, px = j - cq*49;
        float v = s_out[(wv*16+cq)*65 + px];
        s += v; ss += v*v;
      }
      #pragma unroll
      for (int o=32;o>0;o>>=1){ s+=__shfl_down(s,o); ss+=__shfl_down(ss,o); }
      if (l2==0){
        float mean=s/784.f, var=ss/784.f-mean*mean;
        s_stats[wv*2]=mean; s_stats[wv*2+1]=rsqrtf(fmaxf(var,0.f)+1e-5f);
      }
    }
  }
  __syncthreads();
  if (t < 196){
    int px = t>>2, ck = t&3;
    alignas(16) __hip_bfloat16 tmp[8];
    #pragma unroll
    for (int u=0;u<8;u++){
      int chl = ck*8+u;
      int gi = chl>>4;
      float ga = ldin(gamma, (size_t)goff + nbb + chl, isbf);
      float be = ldin(beta,  (size_t)goff + nbb + chl, isbf);
      float v = (s_out[chl*65+px]-s_stats[gi*2])*s_stats[gi*2+1]*ga + be;
      tmp[u] = f2bf(fmaxf(v,0.f));
    }
    *(bfrag*)(out + ((size_t)b*64+px)*CC + nbb + ck*8) = *(const bfrag*)tmp;
  }
}

// ---- conv0 3x3 s2 p1 + GN + ReLU, chunked LDS A, MFMA (validated) --------
__global__ __launch_bounds__(256) void conv0_fused_kernel(
    const __hip_bfloat16* __restrict__ A,     // NHWC [64][196][256]
    const __hip_bfloat16* __restrict__ Wb,    // [9][8][576][32]
    const void* __restrict__ bias,
    const void* __restrict__ gamma, const void* __restrict__ beta,
    const int* __restrict__ flagp,
    __hip_bfloat16* __restrict__ out) {       // NHWC [64][64][576]
  const int t = threadIdx.x;
  const int l = t & 63, w = t >> 6;
  const int wm = w & 1, wn = w >> 1;
  const int ln = l & 15, quad = l >> 4;
  const int b = blockIdx.x, nbb = blockIdx.y*64;

  __shared__ alignas(16) __hip_bfloat16 sC[197*40];
  __shared__ alignas(16) float s_out_arr[64*65];
  __shared__ float s_stats[8];

  if (t < 4){
    bfrag z = {0,0,0,0,0,0,0,0};
    *(bfrag*)(sC + 196*40 + t*8) = z;
  }

  int yy[2], xx[2]; bool pv[2];
  #pragma unroll
  for (int mf=0; mf<2; mf++){
    int p = wm*32 + mf*16 + ln;
    pv[mf] = p<49; yy[mf]=p/7; xx[mf]=p-yy[mf]*7;
  }

  f32x4 acc[2][2];
  #pragma unroll
  for (int i=0;i<2;i++)
    #pragma unroll
    for (int j=0;j<2;j++) acc[i][j] = (f32x4){0.f,0.f,0.f,0.f};

  for (int icb=0; icb<8; icb++){
    __syncthreads();
    for (int idx=t*8; idx<6272; idx+=2048){
      int px = idx>>5, ic = idx&31;
      *(bfrag*)(sC + px*40 + ic) = *(const bfrag*)(A + ((size_t)b*196+px)*256 + icb*32 + ic);
    }
    __syncthreads();
    for (int koff=0; koff<9; koff++){
      const int dy = koff/3 - 1, dx = koff - (koff/3)*3 - 1;
      int sy0=2*yy[0]+dy, sx0=2*xx[0]+dx;
      int r0 = (pv[0]&&sy0>=0&&sy0<14&&sx0>=0&&sx0<14) ? sy0*14+sx0 : 196;
      int sy1=2*yy[1]+dy, sx1=2*xx[1]+dx;
      int r1 = (pv[1]&&sy1>=0&&sy1<14&&sx1>=0&&sx1<14) ? sy1*14+sx1 : 196;
      bfrag a0 = *(const bfrag*)(sC + r0*40 + quad*8);
      bfrag a1 = *(const bfrag*)(sC + r1*40 + quad*8);
      const __hip_bfloat16* wp = Wb + ((size_t)(koff*8+icb)*576 + nbb + wn*32 + ln)*32 + quad*8;
      bfrag b0 = *(const bfrag*)(wp);
      bfrag b1 = *(const bfrag*)(wp + 16*32);
      acc[0][0] = __builtin_amdgcn_mfma_f32_16x16x32_bf16(a0, b0, acc[0][0], 0,0,0);
      acc[1][0] = __builtin_amdgcn_mfma_f32_16x16x32_bf16(a1, b0, acc[1][0], 0,0,0);
      acc[0][1] = __builtin_amdgcn_mfma_f32_16x16x32_bf16(a0, b1, acc[0][1], 0,0,0);
      acc[1][1] = __builtin_amdgcn_mfma_f32_16x16x32_bf16(a1, b1, acc[1][1], 0,0,0);
    }
  }

  epilogue_gn(s_out_arr, s_stats, acc, wm, wn, ln, quad, t,
              bias, 0, gamma, beta, 0, nbb, *flagp, b, out);
}

// ---- depthwise 5x5 per edge: F NHWC -> Y[e][(b*49+px)][64] bf16 ----------
__global__ __launch_bounds__(256) void dw_edge_kernel(
    const __hip_bfloat16* __restrict__ F,
    const void* __restrict__ dw_w,   // [24][64][25]
    const void* __restrict__ dw_b,   // [24][64]
    const int* __restrict__ flagp,
    __hip_bfloat16* __restrict__ Y) {
  const int b = blockIdx.x, e = blockIdx.y, t = threadIdx.x;
  const int isbf = *flagp;
  const int src = EDGE_SRC_C[e];
  __shared__ alignas(16) __hip_bfloat16 sA[50*72];   // 49 px rows + zero row
  for (int idx=t; idx<400; idx+=256){
    if (idx < 392){
      int px = idx>>3, ic = (idx&7)*8;
      *(bfrag*)(sA + px*72 + ic) = *(const bfrag*)(F + ((size_t)b*64+px)*CC + src*64 + ic);
    } else {
      bfrag z = {0,0,0,0,0,0,0,0};
      *(bfrag*)(sA + 49*72 + (idx-392)*8) = z;
    }
  }
  __syncthreads();
  const int ch = t & 63, wv = t >> 6;
  float wd[25];
  #pragma unroll
  for (int j=0;j<25;j++) wd[j] = ldin(dw_w, (size_t)e*1600 + ch*25 + j, isbf);
  float dwb = ldin(dw_b, e*64 + ch, isbf);
  for (int px=wv; px<49; px+=4){
    int oy=px/7, ox=px-oy*7;
    float a = dwb;
    #pragma unroll
    for (int u=0;u<5;u++){
      int py = oy+u-2;
      bool vy = (py>=0)&&(py<7);
      #pragma unroll
      for (int v=0;v<5;v++){
        int pxx = ox+v-2;
        int r = (vy && pxx>=0 && pxx<7) ? py*7+pxx : 49;
        a += bf2f(sA[r*72 + ch]) * wd[u*5+v];
      }
    }
    Y[((size_t)(e*64+b)*49 + px)*64 + ch] = f2bf(a);
  }
}

// ---- pack pointwise weights to bf16 [24][64oc][64ic] ---------------------
__global__ __launch_bounds__(256) void pwpack_kernel(
    const void* __restrict__ pw_fo, const void* __restrict__ pw_so,
    const int* __restrict__ flagp,
    __hip_bfloat16* __restrict__ dfo, __hip_bfloat16* __restrict__ dso) {
  const int e = blockIdx.x, t = threadIdx.x;
  const int isbf = *flagp;
  for (int idx=t; idx<4096; idx+=256){
    dfo[(size_t)e*4096+idx] = f2bf(ldin(pw_fo, (size_t)e*4096+idx, isbf));
    dso[(size_t)e*4096+idx] = f2bf(ldin(pw_so, (size_t)e*4096+idx, isbf));
  }
}

// ---- pointwise + segment-sum via MFMA: out = base + sum_e Y_e @ pw_e^T ---
__global__ __launch_bounds__(256) void pw_seg_kernel(
    const __hip_bfloat16* __restrict__ Y,     // [24][3136][64]
    const __hip_bfloat16* __restrict__ base,  // NHWC [64][64][576]
    const __hip_bfloat16* __restrict__ pwb,   // [24][64oc][64ic] bf16
    const void* __restrict__ pw_b,            // [24][64] ext
    const int* __restrict__ flagp,
    __hip_bfloat16* __restrict__ out) {       // NHWC
  const int t = threadIdx.x, l = t & 63, w = t >> 6;
  const int wm = w & 1, wn = w >> 1;
  const int ln = l & 15, quad = l >> 4;
  const int dst = blockIdx.y;
  const int mt = blockIdx.x*64 + wm*32;
  const int m0 = mt + ln, m1 = m0 + 16;

  f32x4 acc[2][2];
  #pragma unroll
  for (int i=0;i<2;i++)
    #pragma unroll
    for (int j=0;j<2;j++) acc[i][j] = (f32x4){0.f,0.f,0.f,0.f};

  const int eoff = EDGE_OFF_C[dst], ecnt = EDGE_CNT_C[dst];
  for (int k=0;k<ecnt;k++){
    const __hip_bfloat16* Ye = Y + (size_t)(eoff+k)*3136*64;
    const __hip_bfloat16* pe = pwb + (size_t)(eoff+k)*4096;
    #pragma unroll
    for (int ks=0; ks<2; ks++){
      const int kq = ks*32 + quad*8;
      bfrag a0 = *(const bfrag*)(Ye + (size_t)m0*64 + kq);
      bfrag a1 = *(const bfrag*)(Ye + (size_t)m1*64 + kq);
      bfrag b0 = *(const bfrag*)(pe + (wn*32+ln)*64 + kq);
      bfrag b1 = *(const bfrag*)(pe + (wn*32+ln+16)*64 + kq);
      acc[0][0] = __builtin_amdgcn_mfma_f32_16x16x32_bf16(a0, b0, acc[0][0], 0,0,0);
      acc[1][0] = __builtin_amdgcn_mfma_f32_16x16x32_bf16(a1, b0, acc[1][0], 0,0,0);
      acc[0][1] = __builtin_amdgcn_mfma_f32_16x16x32_bf16(a0, b1, acc[0][1], 0,0,0);
      acc[1][1] = __builtin_amdgcn_mfma_f32_16x16x32_bf16(a1, b1, acc[1][1], 0,0,0);
    }
  }

  const int isbf = *flagp;
  #pragma unroll
  for (int nf=0; nf<2; nf++){
    int n = wn*32 + nf*16 + ln;
    float pbs = 0.f;
    for (int k=0;k<ecnt;k++) pbs += ldin(pw_b, (size_t)(eoff+k)*64 + n, isbf);
    #pragma unroll
    for (int mf=0; mf<2; mf++){
      #pragma unroll
      for (int r=0; r<4; r++){
        int m = mt + mf*16 + quad*4 + r;
        int bb = m/49, px = m - bb*49;
        size_t oi = ((size_t)bb*64 + px)*CC + dst*64 + n;
        out[oi] = f2bf(bf2f(base[oi]) + acc[mf][nf][r] + pbs);
      }
    }
  }
}

// ---- up1_w [576][64][16] ext -> wpack [9][16tap][64oc][64ic] bf16 --------
__global__ __launch_bounds__(256) void wpack_dc1_kernel(
    const void* __restrict__ w1, const int* __restrict__ flagp,
    __hip_bfloat16* __restrict__ dst) {
  const int gtap = blockIdx.x, t = threadIdx.x;
  const int isbf = *flagp;
  const int g = gtap >> 4, tap = gtap & 15;
  for (int idx=t; idx<64*64; idx+=256){
    int oc = idx >> 6, ic = idx & 63;
    dst[((size_t)gtap*64 + oc)*64 + ic] =
        f2bf(ldin(w1, ((size_t)(g*64+ic)*64 + oc)*16 + tap, isbf));
  }
}

// ---- deconv1 via MFMA: H NHWC -> mid NHWC [64][196][576] (bias only) -----
__global__ __launch_bounds__(256) void dc1_mfma_kernel(
    const __hip_bfloat16* __restrict__ H,
    const __hip_bfloat16* __restrict__ Wp,   // [g*16+tap][oc][ic]
    const void* __restrict__ b1,
    const int* __restrict__ flagp,
    __hip_bfloat16* __restrict__ mid) {
  const int tid = threadIdx.x;
  const int l = tid & 63;
  const int w = tid >> 6;
  const int wm = w & 1, wn = w >> 1;
  const int g = blockIdx.y;
  const int mt = blockIdx.x*64 + wm*32;
  const int nb = wn*32;
  const int ln = l & 15;
  const int quad = l >> 4;

  int bb[2], iy_t[2][4], ix_t[2][4]; bool vy[2][4], vx[2][4];
  #pragma unroll
  for (int mf=0; mf<2; mf++){
    int m = mt + mf*16 + ln;
    int b = m/196, px = m - b*196;
    bb[mf] = b;
    int oy = px/14, ox = px - oy*14;
    #pragma unroll
    for (int k=0;k<4;k++){
      int ny = oy+1-k; vy[mf][k] = (ny>=0) && !(ny&1) && (ny>>1)<7; iy_t[mf][k]=(ny>>1)*7;
      int nx = ox+1-k; vx[mf][k] = (nx>=0) && !(nx&1) && (nx>>1)<7; ix_t[mf][k]=nx>>1;
    }
  }

  f32x4 acc[2][2];
  #pragma unroll
  for (int i=0;i<2;i++)
    #pragma unroll
    for (int j=0;j<2;j++) acc[i][j] = (f32x4){0.f,0.f,0.f,0.f};
  const bfrag zf = {0,0,0,0,0,0,0,0};

  for (int tap=0; tap<16; tap++){
    const int ky = tap>>2, kx = tap&3;
    int ipx[2]; bool tv[2];
    #pragma unroll
    for (int mf=0; mf<2; mf++){
      tv[mf] = vy[mf][ky] && vx[mf][kx];
      ipx[mf] = iy_t[mf][ky] + ix_t[mf][kx];
    }
    const __hip_bfloat16* wrow = Wp + (((size_t)(g*16+tap)*64 + nb + ln)*64);
    #pragma unroll
    for (int half=0; half<2; half++){
      const int icq = half*32 + quad*8;
      bfrag a0 = tv[0] ? *(const bfrag*)(H + ((size_t)(bb[0]*64 + ipx[0]))*CC + g*64 + icq) : zf;
      bfrag a1 = tv[1] ? *(const bfrag*)(H + ((size_t)(bb[1]*64 + ipx[1]))*CC + g*64 + icq) : zf;
      bfrag b0 = *(const bfrag*)(wrow + icq);
      bfrag b1v = *(const bfrag*)(wrow + 16*64 + icq);
      acc[0][0] = __builtin_amdgcn_mfma_f32_16x16x32_bf16(a0, b0,  acc[0][0], 0,0,0);
      acc[1][0] = __builtin_amdgcn_mfma_f32_16x16x32_bf16(a1, b0,  acc[1][0], 0,0,0);
      acc[0][1] = __builtin_amdgcn_mfma_f32_16x16x32_bf16(a0, b1v, acc[0][1], 0,0,0);
      acc[1][1] = __builtin_amdgcn_mfma_f32_16x16x32_bf16(a1, b1v, acc[1][1], 0,0,0);
    }
  }

  const int isbf = *flagp;
  #pragma unroll
  for (int nf=0; nf<2; nf++){
    int n = g*64 + nb + nf*16 + ln;
    float bv = ldin(b1, n, isbf);
    #pragma unroll
    for (int mf=0; mf<2; mf++){
      #pragma unroll
      for (int r=0; r<4; r++){
        int m = mt + mf*16 + quad*4 + r;
        int b = m/196, px = m - b*196;
        mid[((size_t)b*196 + px)*CC + n] = f2bf(acc[mf][nf][r] + bv);
      }
    }
  }
}

// ---- fused GN(9)+ReLU+deconv2: mid NHWC -> out 28x28, split in 2 halves --
// grid (b, g, z): z=0 -> out rows 0..13 (in rows 0..7), z=1 -> 14..27 (6..13)
__global__ __launch_bounds__(256) void dc2gn_kernel(
    const __hip_bfloat16* __restrict__ mid,   // [64][196][576] (bias only)
    const void* __restrict__ gamma, const void* __restrict__ beta,
    const void* __restrict__ w2,
    const void* __restrict__ b2,
    const int* __restrict__ flagp,
    void* __restrict__ outp,
    size_t out_elem_off) {
  const int isbf = *flagp;
  const int b=blockIdx.x, g=blockIdx.y, z=blockIdx.z, t=threadIdx.x;
  const int c = t & 63;
  __shared__ __hip_bfloat16 s_mid[64*113];   // [c][8 rows x 14 cols + pad]
  __shared__ float s_w2[64][17];
  __shared__ float red[8]; __shared__ float stats[2];
  const __hip_bfloat16* mbase = mid + (size_t)b*196*CC + g*64;

  // group stats (redundant per z-half; streams 25 KB from L2)
  {
    float s=0.f, ss=0.f;
    for (int idx=t; idx<12544; idx+=256){
      int ipx = idx>>6;
      float v = bf2f(mbase[(size_t)ipx*CC + (idx&63)]);
      s+=v; ss+=v*v;
    }
    #pragma unroll
    for (int o=32;o>0;o>>=1){ s+=__shfl_down(s,o); ss+=__shfl_down(ss,o); }
    int wid=t>>6;
    if ((t&63)==0){ red[wid]=s; red[4+wid]=ss; }
  }
  for (int idx=t; idx<1024; idx+=256)
    s_w2[idx>>4][idx&15] = ldin(w2, (g*SPC + (idx>>4))*16 + (idx&15), isbf);
  __syncthreads();
  if (t==0){
    float S=red[0]+red[1]+red[2]+red[3];
    float SS=red[4]+red[5]+red[6]+red[7];
    float mean=S/12544.f, var=SS/12544.f-mean*mean;
    stats[0]=mean; stats[1]=rsqrtf(fmaxf(var,0.f)+1e-5f);
  }
  __syncthreads();
  const float mean=stats[0], inv=stats[1];
  const int rbase = z*6;                 // input rows rbase..rbase+7
  {
    float ga = ldin(gamma, g*SPC+c, isbf), be = ldin(beta, g*SPC+c, isbf);
    for (int idx=t; idx<7168; idx+=256){
      int pl = idx>>6;                   // c = idx&63 == t&63 (stride 256)
      int ipx = (rbase + pl/14)*14 + (pl%14);
      float v = (bf2f(mbase[(size_t)ipx*CC + c])-mean)*inv*ga + be;
      s_mid[c*113 + pl] = f2bf(fmaxf(v, 0.f));
    }
  }
  __syncthreads();
  float b2v = ldin(b2, g, isbf);
  for (int p=t; p<392; p+=256){
    int oyl = p/28, ox = p - oyl*28;
    int oy = z*14 + oyl;
    float a = b2v;
    for (int cc=0; cc<64; cc++){
      #pragma unroll
      for (int kyi=0;kyi<2;kyi++){
        int ky=((oy+1)&1)+2*kyi; int ny=oy+1-ky;
        if (ny>=0){
          int iy=ny>>1;
          if (iy<14){
            int li = iy - rbase;     // in [0,8) by construction
            #pragma unroll
            for (int kxi=0;kxi<2;kxi++){
              int kx=((ox+1)&1)+2*kxi; int nx=ox+1-kx;
              if (nx>=0){
                int ix=nx>>1;
                if (ix<14) a += bf2f(s_mid[cc*113 + li*14 + ix])*s_w2[cc][ky*4+kx];
              }
            }
          }
        }
      }
    }
    size_t oidx = out_elem_off + ((size_t)b*NGR+g)*HW28 + oy*28 + ox;
    if (isbf) ((__hip_bfloat16*)outp)[oidx] = f2bf(a);
    else      ((float*)outp)[oidx] = a;
  }
}

extern "C" void kernel_launch(void* const* d_in, const int* in_sizes, int n_in,
                              void* d_out, int out_size, void* d_ws, size_t ws_size,
                              hipStream_t stream) {
  const void* x        = d_in[0];
  const void* convs_w0 = d_in[1];
  const void* convs_b0 = d_in[2];
  const void* convs_w  = d_in[3];
  const void* convs_b  = d_in[4];
  const void* gn_gamma = d_in[5];
  const void* gn_beta  = d_in[6];
  const void* fo_dw_w  = d_in[7];
  const void* fo_dw_b  = d_in[8];
  const void* fo_pw_w  = d_in[9];
  const void* fo_pw_b  = d_in[10];
  const void* so_dw_w  = d_in[11];
  const void* so_dw_b  = d_in[12];
  const void* so_pw_w  = d_in[13];
  const void* so_pw_b  = d_in[14];
  const void* up1_w    = d_in[15];
  const void* up1_b    = d_in[16];
  const void* sbn_g    = d_in[17];
  const void* sbn_b    = d_in[18];
  const void* up2_w    = d_in[19];
  const void* up2_b    = d_in[20];
  (void)in_sizes; (void)n_in; (void)out_size; (void)ws_size;

  int* flag = (int*)d_ws;
  char* wsb = (char*)d_ws + 16;
  __hip_bfloat16* act0   = (__hip_bfloat16*)(wsb);
  __hip_bfloat16* wbuf   = (__hip_bfloat16*)(wsb + 6422528);
  __hip_bfloat16* actA   = (__hip_bfloat16*)(wsb + 12394496);
  __hip_bfloat16* actB   = (__hip_bfloat16*)(wsb + 17113088);
  __hip_bfloat16* bufF   = (__hip_bfloat16*)(wsb + 21831680);
  __hip_bfloat16* secN   = (__hip_bfloat16*)(wsb + 26550272);
  __hip_bfloat16* wpack  = (__hip_bfloat16*)(wsb + 31268864);
  __hip_bfloat16* pwbF   = (__hip_bfloat16*)(wsb + 32448512);
  __hip_bfloat16* pwbS   = (__hip_bfloat16*)(wsb + 32645120);
  __hip_bfloat16* Y      = (__hip_bfloat16*)(wsb);
  __hip_bfloat16* mid    = (__hip_bfloat16*)(wsb);

  detect_kernel<<<1, 1, 0, stream>>>((const unsigned short*)x, flag);

  xcvt_kernel<<<dim3(BB,8,7), 256, 0, stream>>>(x, flag, act0);
  wcvt0_kernel<<<CC, 256, 0, stream>>>(convs_w0, flag, wbuf);
  conv0_fused_kernel<<<dim3(64,9), 256, 0, stream>>>(
      act0, wbuf, convs_b0, gn_gamma, gn_beta, flag, actA);

  __hip_bfloat16* cur = actA; __hip_bfloat16* nxt = actB;
  for (int i=0;i<7;i++){
    wcvtL_kernel<<<CC, 256, 0, stream>>>(convs_w, i, flag, wbuf);
    conv3_v3_kernel<<<dim3(64,18), 256, 0, stream>>>(
        cur, wbuf, convs_b, i*CC, gn_gamma, gn_beta, (i+1)*CC, flag, nxt);
    __hip_bfloat16* tmp=cur; cur=nxt; nxt=tmp;
  }
  // cur == actB (h, NHWC)

  wpack_dc1_kernel<<<144, 256, 0, stream>>>(up1_w, flag, wpack);
  pwpack_kernel<<<24, 256, 0, stream>>>(fo_pw_w, so_pw_w, flag, pwbF, pwbS);

  // edge pass 1: first = h + seg(pw(dw(h)))
  dw_edge_kernel<<<dim3(BB,24), 256, 0, stream>>>(cur, fo_dw_w, fo_dw_b, flag, Y);
  pw_seg_kernel<<<dim3(49,NGR), 256, 0, stream>>>(Y, cur, pwbF, fo_pw_b, flag, bufF);
  // edge pass 2: second = h + seg(pw(dw(first)))
  dw_edge_kernel<<<dim3(BB,24), 256, 0, stream>>>(bufF, so_dw_w, so_dw_b, flag, Y);
  pw_seg_kernel<<<dim3(49,NGR), 256, 0, stream>>>(Y, cur, pwbS, so_pw_b, flag, secN);

  // head 1 (input h = cur, NHWC)
  dc1_mfma_kernel<<<dim3(196,NGR), 256, 0, stream>>>(cur, wpack, up1_b, flag, mid);
  dc2gn_kernel<<<dim3(BB,NGR,2), 256, 0, stream>>>(mid, sbn_g, sbn_b, up2_w, up2_b, flag, d_out, 0);
  // head 2 (input secN, NHWC)
  dc1_mfma_kernel<<<dim3(196,NGR), 256, 0, stream>>>(secN, wpack, up1_b, flag, mid);
  dc2gn_kernel<<<dim3(BB,NGR,2), 256, 0, stream>>>(mid, sbn_g, sbn_b, up2_w, up2_b, flag, d_out, (size_t)BB*NGR*HW28);
}